// Round 3
// baseline (954.942 us; speedup 1.0000x reference)
//
#include <hip/hip_runtime.h>
#include <stdint.h>
#include <stddef.h>

#define T_LEN   2000
#define BATCH   32
#define ROWS    64000      /* B*T */
#define KDIM    1024
#define ADIM    512
#define CCH     32
#define KW      101        /* 2*50+1 */

typedef _Float16 half8_t  __attribute__((ext_vector_type(8)));
typedef _Float16 half4_t  __attribute__((ext_vector_type(4)));
typedef float    float4_t __attribute__((ext_vector_type(4)));

__device__ __forceinline__ half8_t pack8(float4_t a, float4_t b) {
    half8_t r;
    r[0] = (_Float16)a.x; r[1] = (_Float16)a.y;
    r[2] = (_Float16)a.z; r[3] = (_Float16)a.w;
    r[4] = (_Float16)b.x; r[5] = (_Float16)b.y;
    r[6] = (_Float16)b.z; r[7] = (_Float16)b.w;
    return r;
}

__device__ __forceinline__ float tanh_fast(float x) {
    float ax = __builtin_fabsf(x);
    ax = fminf(ax, 15.f);
    float e = __expf(2.f * ax);
    float t = 1.f - 2.f * __builtin_amdgcn_rcpf(e + 1.f);
    return (x < 0.f) ? -t : t;
}

/* async global->LDS, 16B/lane; LDS dest = wave-uniform base + lane*16 */
__device__ __forceinline__ void glds16(const void* g, void* l) {
    __builtin_amdgcn_global_load_lds((const __attribute__((address_space(1))) uint32_t*)g,
                                     (__attribute__((address_space(3))) uint32_t*)l,
                                     16, 0, 0);
}

/* ---- ws layouts (bytes) ---- */
#define OFF_WENCT 0
#define OFF_WATTT 1048576
#define OFF_CONV  1081344
#define M_DTERM   5177344
#define M_EPART   5242880
#define M_CPART   6266880
#define M_ENCH    8364032
#define F_DTERM   9273344
#define F_EPART   9338880
#define F_CPART   10362880

/* ---- fused prep: [0,512) We transpose, [512,640) dterm, [640,1152) conv,
 *      [1152] Wat, [1153, 1153+8000) enc->f16 conversion (8192 elems/blk, main) */
__global__ __launch_bounds__(256) void k_prep(const float* __restrict__ We,
                                              const float* __restrict__ Wa,
                                              const float* __restrict__ dec_h,
                                              const float* __restrict__ W_dec,
                                              const float* __restrict__ be,
                                              const float* __restrict__ bd,
                                              const float* __restrict__ ba,
                                              const float* __restrict__ att_prev,
                                              const float* __restrict__ conv_w,
                                              const float* __restrict__ enc,
                                              _Float16* __restrict__ Wet,
                                              _Float16* __restrict__ Wat,
                                              float* __restrict__ dterm,
                                              void* __restrict__ convO,
                                              _Float16* __restrict__ encH,
                                              int f16mode) {
    __shared__ float smem[3460];
    const int blk = blockIdx.x, tid = threadIdx.x;

    if (blk >= 1153) {
        /* enc fp32 -> f16, 8192 elems/block */
        const size_t base = (size_t)(blk - 1153) * 8192 + (size_t)tid * 8;
#pragma unroll
        for (int i = 0; i < 4; ++i) {
            const size_t idx = base + (size_t)i * 2048;
            const float4_t* s = (const float4_t*)(enc + idx);
            *(half8_t*)(encH + idx) = pack8(s[0], s[1]);
        }
        return;
    }
    if (blk < 512) {
        float (*tile)[33] = (float(*)[33])smem;
        const int k0 = (blk >> 4) * 32, n0 = (blk & 15) * 32;
        const int tx = tid & 31, ty = tid >> 5;
#pragma unroll
        for (int i = 0; i < 4; ++i)
            tile[ty + i * 8][tx] = We[(size_t)(k0 + ty + i * 8) * ADIM + n0 + tx];
        __syncthreads();
#pragma unroll
        for (int i = 0; i < 4; ++i)
            Wet[(size_t)(n0 + ty + i * 8) * KDIM + k0 + tx] = (_Float16)tile[tx][ty + i * 8];
    } else if (blk < 640) {
        float* dh = smem;
        float* part = smem + 1024;
        const int idx = blk - 512, b = idx >> 2, a0 = (idx & 3) * 128;
#pragma unroll
        for (int i = 0; i < 4; ++i) dh[tid + i * 256] = dec_h[b * KDIM + tid + i * 256];
        __syncthreads();
        const int a = a0 + (tid & 127), kh = (tid >> 7) * 512;
        float s = 0.f;
#pragma unroll 8
        for (int k = 0; k < 512; ++k) s += dh[kh + k] * W_dec[(size_t)(kh + k) * ADIM + a];
        part[tid] = s;
        __syncthreads();
        if (tid < 128) {
            const int aa = a0 + tid;
            dterm[b * ADIM + aa] = part[tid] + part[tid + 128] + be[aa] + bd[aa] + ba[aa];
        }
    } else if (blk < 1152) {
        float* ap = smem;
        float* w  = smem + 228;
        const int idx = blk - 640, b = idx >> 4, tt = idx & 15;
        const int t0 = tt * 128;
        for (int i = tid; i < 228; i += 256) {
            int t = t0 - 50 + i;
            ap[i] = (t >= 0 && t < T_LEN) ? att_prev[b * T_LEN + t] : 0.f;
        }
        for (int i = tid; i < CCH * KW; i += 256) w[i] = conv_w[i];
        __syncthreads();
        for (int idx2 = tid; idx2 < 128 * CCH; idx2 += 256) {
            int tl = idx2 >> 5, c = idx2 & 31;
            int t = t0 + tl;
            if (t < T_LEN) {
                float s = 0.f;
#pragma unroll
                for (int j = 0; j < KW; ++j) s += ap[tl + j] * w[c * KW + j];
                const size_t o = (size_t)(b * T_LEN + t) * CCH + c;
                if (f16mode) ((_Float16*)convO)[o] = (_Float16)s;
                else         ((float*)convO)[o] = s;
            }
        }
    } else {
#pragma unroll
        for (int rr = 0; rr < 2; ++rr) {
            const int n = tid * 2 + rr;
#pragma unroll
            for (int c = 0; c < CCH; ++c)
                Wat[n * CCH + c] = (_Float16)Wa[c * ADIM + n];
        }
    }
}

/* =====================================================================
 * Main-path fused GEMM+tanh+dot, 8-wave occupancy version.
 * 1000 blocks (XCD-swizzled: both nc-siblings of an m-tile on one XCD),
 * 512 thr = 8 waves (2m x 4n), tile 128x256, wave 64x64, BK=32.
 * 2-buffer LDS (A 8KB + B 16KB per buf = 48KB total -> 3 blocks/CU =
 * 24 waves/CU), proven syncthreads schedule, 3 glds16/wave/step.
 * epart has 2 nc-planes.
 * ===================================================================== */
__global__ __launch_bounds__(512, 6)
void k_gemm_h(const _Float16* __restrict__ encH,
              const _Float16* __restrict__ Wet,
              const _Float16* __restrict__ cvH,
              const _Float16* __restrict__ Wat,
              const float* __restrict__ dterm,
              const float* __restrict__ gvec,
              float* __restrict__ epart) {
    __shared__ __attribute__((aligned(16))) char Ab[2][8192];
    __shared__ __attribute__((aligned(16))) char Bh[2][16384];

    const int tid  = threadIdx.x;
    const int blk  = blockIdx.x;
    /* 1000 blocks: groups of 16 = {nc0 x 8 mt, nc1 x same 8 mt} -> same XCD */
    int nc, mt;
    if (blk < 992) { nc = (blk >> 3) & 1; mt = (blk >> 4) * 8 + (blk & 7); }
    else           { int r = blk - 992; nc = r >> 2; mt = 496 + (r & 3); }
    const int m0 = mt * 128, n0 = nc * 256;

    const int wave = tid >> 6, lane = tid & 63;
    const int quad = lane >> 4, c16 = lane & 15;
    const int wm = (wave >> 2) * 64, wn = (wave & 3) * 64;
    const int rl = lane & 15, sg = lane >> 4;   /* staging: seg-major 16B lanes */

    /* staging rows: wave stages A-chunk `wave` (16 rows) + B-chunks 2w,2w+1 */
    const size_t aRow  = (size_t)(m0 + wave * 16 + rl);
    const size_t bRow0 = (size_t)(n0 + (2 * wave) * 16 + rl);
    const size_t bRow1 = bRow0 + 16;

    /* epilogue data */
    float g[4], dt0[4], dt1[4];
    const int b0 = m0 / T_LEN, b1 = (m0 + 127) / T_LEN;
    const int lim = (b0 + 1) * T_LEN;
#pragma unroll
    for (int j = 0; j < 4; ++j) {
        const int col = n0 + wn + j * 16 + c16;
        g[j]   = gvec[col];
        dt0[j] = dterm[b0 * ADIM + col];
        dt1[j] = dterm[b1 * ADIM + col];
    }

    float4_t acc[4][4];
#pragma unroll
    for (int i = 0; i < 4; ++i)
#pragma unroll
        for (int j = 0; j < 4; ++j) acc[i][j] = (float4_t){0.f, 0.f, 0.f, 0.f};

#define STG(bf, Abase, Bbase, stride, kn)                                          \
    glds16((Abase) + aRow  * (stride) + (kn) + sg * 8, &Ab[bf][wave * 1024]);      \
    glds16((Bbase) + bRow0 * (stride) + (kn) + sg * 8, &Bh[bf][(2 * wave) * 1024]);\
    glds16((Bbase) + bRow1 * (stride) + (kn) + sg * 8, &Bh[bf][(2 * wave + 1) * 1024]);

    /* prologue */
    STG(0, encH, Wet, KDIM, 0)
    __syncthreads();

    for (int kk = 0; kk < 33; ++kk) {
        const int cur = kk & 1, nxt = cur ^ 1;
        if (kk < 31) {
            const int kn = (kk + 1) * 32;
            STG(nxt, encH, Wet, KDIM, kn)
        } else if (kk == 31) {   /* conv K-step */
            STG(nxt, cvH, Wat, CCH, 0)
        }
        half8_t af[4], bf4[4];
        const _Float16* Ah = (const _Float16*)Ab[cur];
        const _Float16* Bp = (const _Float16*)Bh[cur];
#pragma unroll
        for (int i = 0; i < 4; ++i)
            af[i] = *(const half8_t*)(Ah + (wm / 16 + i) * 512 + lane * 8);
#pragma unroll
        for (int j = 0; j < 4; ++j)
            bf4[j] = *(const half8_t*)(Bp + (wn / 16 + j) * 512 + lane * 8);
#pragma unroll
        for (int i = 0; i < 4; ++i)
#pragma unroll
            for (int j = 0; j < 4; ++j)
                acc[i][j] = __builtin_amdgcn_mfma_f32_16x16x32_f16(af[i], bf4[j], acc[i][j], 0, 0, 0);
        __syncthreads();
    }
#undef STG

    /* epilogue: + dterm, tanh, *g, 16-lane reduce, combine 4 n-waves */
    float* e_lds = (float*)Bh[0];   /* [128][4] floats = 2KB */
#pragma unroll
    for (int i = 0; i < 4; ++i) {
#pragma unroll
        for (int r = 0; r < 4; ++r) {
            const int rloc = wm + i * 16 + quad * 4 + r;
            const bool hi = (m0 + rloc) >= lim;
            float s = 0.f;
#pragma unroll
            for (int j = 0; j < 4; ++j)
                s += tanh_fast(acc[i][j][r] + (hi ? dt1[j] : dt0[j])) * g[j];
#pragma unroll
            for (int off = 1; off < 16; off <<= 1) s += __shfl_xor(s, off);
            if (c16 == 0) e_lds[rloc * 4 + (wave & 3)] = s;
        }
    }
    __syncthreads();
    if (tid < 128) {
        const float4_t q = ((const float4_t*)e_lds)[tid];
        epart[nc * ROWS + m0 + tid] = q.x + q.y + q.z + q.w;
    }
}

/* fallback-path GEMM (fp32 A), original 2-buffer structure, 4 nc-planes */
__global__ __launch_bounds__(256, 3)
void k_gemm_f(const float* __restrict__ encF,
              const _Float16* __restrict__ Wet,
              const float* __restrict__ cvF,
              const _Float16* __restrict__ Wat,
              const float* __restrict__ dterm,
              const float* __restrict__ gvec,
              float* __restrict__ epart) {
    __shared__ __attribute__((aligned(16))) char     Ab[2][16384];
    __shared__ __attribute__((aligned(16))) _Float16 Bh[2][128 * 32];

    const int tid  = threadIdx.x;
    const int blk  = blockIdx.x;
    int nc, mt;
    if (blk < 1984) { nc = (blk >> 3) & 3; mt = (blk >> 5) * 8 + (blk & 7); }
    else            { int r = blk - 1984; nc = r >> 2; mt = 496 + (r & 3); }
    const int m0 = mt * 128, n0 = nc * 128;

    const int wave = tid >> 6, lane = tid & 63;
    const int quad = lane >> 4, c16 = lane & 15;
    const int wm = (wave >> 1) * 64, wn = (wave & 1) * 64;

    const int rlB = lane & 15, sgB = lane >> 4;
    const int rlA = lane & 7,  sgA = lane >> 3;

    const size_t aRow = (size_t)(m0 + wave * 32 + rlA);
    const size_t bRow = (size_t)(n0 + wave * 32 + rlB);

    float g[4], dt0[4], dt1[4];
    const int b0 = m0 / T_LEN, b1 = (m0 + 127) / T_LEN;
    const int lim = (b0 + 1) * T_LEN;
#pragma unroll
    for (int j = 0; j < 4; ++j) {
        const int col = n0 + wn + j * 16 + c16;
        g[j]   = gvec[col];
        dt0[j] = dterm[b0 * ADIM + col];
        dt1[j] = dterm[b1 * ADIM + col];
    }

    float4_t acc[4][4];
#pragma unroll
    for (int i = 0; i < 4; ++i)
#pragma unroll
        for (int j = 0; j < 4; ++j) acc[i][j] = (float4_t){0.f, 0.f, 0.f, 0.f};

#define STAGE_A(buf, base, stride, k0)                                              \
    _Pragma("unroll")                                                               \
    for (int i = 0; i < 4; ++i)                                                     \
        glds16((base) + ((aRow + i * 8) * (stride)) + (k0) + sgA * 4,               \
               &Ab[buf][(wave * 4 + i) * 1024]);
#define STAGE_B(buf, base, stride, k0)                                              \
    _Pragma("unroll")                                                               \
    for (int i = 0; i < 2; ++i)                                                     \
        glds16((base) + ((bRow + i * 16) * (stride)) + (k0) + sgB * 8,              \
               (char*)&Bh[buf][0] + (wave * 2 + i) * 1024);

    STAGE_A(0, encF, KDIM, 0)
    STAGE_B(0, Wet, KDIM, 0)
    __syncthreads();

    for (int kk = 0; kk < 33; ++kk) {
        const int cur = kk & 1, nxt = cur ^ 1;
        if (kk < 31) {
            const int kn = (kk + 1) * 32;
            STAGE_A(nxt, encF, KDIM, kn)
            STAGE_B(nxt, Wet, KDIM, kn)
        } else if (kk == 31) {
            STAGE_A(nxt, cvF, CCH, 0)
            STAGE_B(nxt, Wat, CCH, 0)
        }
        half8_t af[4], bf[4];
        const float* Afp = (const float*)Ab[cur];
#pragma unroll
        for (int i = 0; i < 4; ++i) {
            const int row = wm + i * 16 + c16;
            const float* cb = Afp + (row >> 3) * 256 + (row & 7) * 4;
            float4_t u0 = *(const float4_t*)(cb + (2 * quad) * 32);
            float4_t u1 = *(const float4_t*)(cb + (2 * quad + 1) * 32);
            af[i] = pack8(u0, u1);
        }
#pragma unroll
        for (int j = 0; j < 4; ++j) {
            const int row = wn + j * 16 + c16;
            bf[j] = *(const half8_t*)(&Bh[cur][0] + (row >> 4) * 512 + (quad * 16 + c16) * 8);
        }
#pragma unroll
        for (int i = 0; i < 4; ++i)
#pragma unroll
            for (int j = 0; j < 4; ++j)
                acc[i][j] = __builtin_amdgcn_mfma_f32_16x16x32_f16(af[i], bf[j], acc[i][j], 0, 0, 0);
        __syncthreads();
    }
#undef STAGE_A
#undef STAGE_B

    float* e_lds = (float*)&Bh[0][0];
#pragma unroll
    for (int i = 0; i < 4; ++i) {
#pragma unroll
        for (int r = 0; r < 4; ++r) {
            const int rloc = wm + i * 16 + quad * 4 + r;
            const bool hi = (m0 + rloc) >= lim;
            float s = 0.f;
#pragma unroll
            for (int j = 0; j < 4; ++j)
                s += tanh_fast(acc[i][j][r] + (hi ? dt1[j] : dt0[j])) * g[j];
#pragma unroll
            for (int off = 1; off < 16; off <<= 1) s += __shfl_xor(s, off);
            if (c16 == 0) e_lds[rloc * 2 + (wave & 1)] = s;
        }
    }
    __syncthreads();
    if (tid < 128) {
        const float2 q = ((const float2*)e_lds)[tid];
        epart[nc * ROWS + m0 + tid] = q.x + q.y;
    }
}

/* softmax over T; logit = 2*sum_{p<np} epart[p], masked -> -2e15 */
__global__ __launch_bounds__(512) void k_softmax(const float* __restrict__ epart,
                                                 const int* __restrict__ enc_len,
                                                 float* __restrict__ attn,
                                                 int np) {
    __shared__ float ex[T_LEN];
    __shared__ float red[8];
    const int b = blockIdx.x, tid = threadIdx.x;
    const int len = enc_len[b];
    float lmax = -3.4e38f;
    for (int t = tid; t < T_LEN; t += 512) {
        float e = epart[b * T_LEN + t];
        for (int p = 1; p < np; ++p) e += epart[p * ROWS + b * T_LEN + t];
        float lg = (t < len) ? 2.f * e : -2e15f;
        ex[t] = lg;
        lmax = fmaxf(lmax, lg);
    }
    for (int off = 1; off < 64; off <<= 1) lmax = fmaxf(lmax, __shfl_xor(lmax, off));
    if ((tid & 63) == 0) red[tid >> 6] = lmax;
    __syncthreads();
    const float m = fmaxf(fmaxf(fmaxf(red[0], red[1]), fmaxf(red[2], red[3])),
                          fmaxf(fmaxf(red[4], red[5]), fmaxf(red[6], red[7])));
    float lsum = 0.f;
    for (int t = tid; t < T_LEN; t += 512) {
        float p = __expf(ex[t] - m);
        ex[t] = p;
        lsum += p;
    }
    for (int off = 1; off < 64; off <<= 1) lsum += __shfl_xor(lsum, off);
    __syncthreads();
    if ((tid & 63) == 0) red[tid >> 6] = lsum;
    __syncthreads();
    const float inv = 1.f / (red[0] + red[1] + red[2] + red[3] + red[4] + red[5] + red[6] + red[7]);
    for (int t = tid; t < T_LEN; t += 512) attn[b * T_LEN + t] = ex[t] * inv;
}

/* c partial from f16 enc copy */
__global__ __launch_bounds__(256) void k_cpart_h(const float* __restrict__ attn,
                                                 const _Float16* __restrict__ encH,
                                                 float* __restrict__ cpart) {
    const int b = blockIdx.y, tc = blockIdx.x, tid = threadIdx.x;
    const int t0 = tc * 125;
    float4_t s = (float4_t){0.f, 0.f, 0.f, 0.f};
    const half4_t* ep = (const half4_t*)(encH + (size_t)b * T_LEN * KDIM) + tid;
    const float* ap = attn + b * T_LEN + t0;
#pragma unroll 5
    for (int tt = 0; tt < 125; ++tt) {
        const float w = ap[tt];
        half4_t v = ep[(size_t)(t0 + tt) * 256];
        s.x += w * (float)v[0]; s.y += w * (float)v[1];
        s.z += w * (float)v[2]; s.w += w * (float)v[3];
    }
    *(float4_t*)&cpart[(size_t)(tc * BATCH + b) * KDIM + tid * 4] = s;
}

/* c partial from fp32 enc (fallback) */
__global__ __launch_bounds__(256) void k_cpart_f(const float* __restrict__ attn,
                                                 const float* __restrict__ enc,
                                                 float* __restrict__ cpart) {
    const int b = blockIdx.y, tc = blockIdx.x, tid = threadIdx.x;
    const int t0 = tc * 125;
    float4_t s = (float4_t){0.f, 0.f, 0.f, 0.f};
    const float4_t* ep = (const float4_t*)(enc + (size_t)b * T_LEN * KDIM) + tid;
    const float* ap = attn + b * T_LEN + t0;
#pragma unroll 5
    for (int tt = 0; tt < 125; ++tt) {
        const float w = ap[tt];
        float4_t v = ep[(size_t)(t0 + tt) * 256];
        s += v * w;
    }
    *(float4_t*)&cpart[(size_t)(tc * BATCH + b) * KDIM + tid * 4] = s;
}

/* out_c[b][o] = b_o[o] + sum_d (sum_p cpart[p][b][d]) * W_o[d][o] ; grid (32,4) x 256 */
__global__ __launch_bounds__(256) void k_out(const float* __restrict__ cpart,
                                             const float* __restrict__ W_o,
                                             const float* __restrict__ b_o,
                                             float* __restrict__ out_c) {
    __shared__ float cm[KDIM];
    const int b = blockIdx.x, tid = threadIdx.x;
    for (int d = tid; d < KDIM; d += 256) {
        float s = 0.f;
#pragma unroll
        for (int p = 0; p < 16; ++p) s += cpart[(size_t)(p * BATCH + b) * KDIM + d];
        cm[d] = s;
    }
    __syncthreads();
    const int o = blockIdx.y * 256 + tid;
    float s = b_o[o];
#pragma unroll 8
    for (int d = 0; d < KDIM; ++d) s += cm[d] * W_o[(size_t)d * KDIM + o];
    out_c[b * KDIM + o] = s;
}

extern "C" void kernel_launch(void* const* d_in, const int* in_sizes, int n_in,
                              void* d_out, int out_size, void* d_ws, size_t ws_size,
                              hipStream_t stream) {
    const float* enc      = (const float*)d_in[0];
    const int*   enc_len  = (const int*)d_in[1];
    const float* dec_h    = (const float*)d_in[2];
    const float* att_prev = (const float*)d_in[3];
    const float* W_enc    = (const float*)d_in[4];
    const float* b_enc    = (const float*)d_in[5];
    const float* W_dec    = (const float*)d_in[6];
    const float* b_dec    = (const float*)d_in[7];
    const float* W_att    = (const float*)d_in[8];
    const float* b_att    = (const float*)d_in[9];
    const float* conv_w   = (const float*)d_in[10];
    const float* gvec     = (const float*)d_in[11];
    const float* W_o      = (const float*)d_in[12];
    const float* b_o      = (const float*)d_in[13];

    float* out_c    = (float*)d_out;           /* 32*1024 */
    float* out_attn = out_c + BATCH * KDIM;    /* 32*2000 */

    char* ws = (char*)d_ws;
    _Float16* Wet = (_Float16*)(ws + OFF_WENCT);
    _Float16* Wat = (_Float16*)(ws + OFF_WATTT);

    const size_t needMain = (size_t)M_ENCH + (size_t)ROWS * KDIM * 2;
    const bool f16p = ws_size >= needMain;

    if (f16p) {
        _Float16* convH = (_Float16*)(ws + OFF_CONV);
        float*    dterm = (float*)(ws + M_DTERM);
        float*    epart = (float*)(ws + M_EPART);
        float*    cpart = (float*)(ws + M_CPART);
        _Float16* encH  = (_Float16*)(ws + M_ENCH);

        k_prep<<<1153 + 8000, 256, 0, stream>>>(W_enc, W_att, dec_h, W_dec, b_enc, b_dec,
                                                b_att, att_prev, conv_w, enc,
                                                Wet, Wat, dterm, convH, encH, 1);
        k_gemm_h<<<1000, 512, 0, stream>>>(encH, Wet, convH, Wat, dterm, gvec, epart);
        k_softmax<<<BATCH, 512, 0, stream>>>(epart, enc_len, out_attn, 2);
        k_cpart_h<<<dim3(16, BATCH), 256, 0, stream>>>(out_attn, encH, cpart);
        k_out<<<dim3(BATCH, 4), 256, 0, stream>>>(cpart, W_o, b_o, out_c);
    } else {
        float* convF = (float*)(ws + OFF_CONV);
        float* dterm = (float*)(ws + F_DTERM);
        float* epart = (float*)(ws + F_EPART);
        float* cpart = (float*)(ws + F_CPART);

        k_prep<<<1153, 256, 0, stream>>>(W_enc, W_att, dec_h, W_dec, b_enc, b_dec,
                                         b_att, att_prev, conv_w, enc,
                                         Wet, Wat, dterm, convF, (_Float16*)nullptr, 0);
        k_gemm_f<<<2000, 256, 0, stream>>>(enc, Wet, convF, Wat, dterm, gvec, epart);
        k_softmax<<<BATCH, 512, 0, stream>>>(epart, enc_len, out_attn, 4);
        k_cpart_f<<<dim3(16, BATCH), 256, 0, stream>>>(out_attn, enc, cpart);
        k_out<<<dim3(BATCH, 4), 256, 0, stream>>>(cpart, W_o, b_o, out_c);
    }
}

// Round 4
// 684.934 us; speedup vs baseline: 1.3942x; 1.3942x over previous
//
#include <hip/hip_runtime.h>
#include <stdint.h>
#include <stddef.h>

#define T_LEN   2000
#define BATCH   32
#define ROWS    64000      /* B*T */
#define KDIM    1024
#define ADIM    512
#define CCH     32
#define KW      101        /* 2*50+1 */

typedef _Float16 half8_t  __attribute__((ext_vector_type(8)));
typedef _Float16 half4_t  __attribute__((ext_vector_type(4)));
typedef float    float4_t __attribute__((ext_vector_type(4)));

__device__ __forceinline__ half8_t pack8(float4_t a, float4_t b) {
    half8_t r;
    r[0] = (_Float16)a.x; r[1] = (_Float16)a.y;
    r[2] = (_Float16)a.z; r[3] = (_Float16)a.w;
    r[4] = (_Float16)b.x; r[5] = (_Float16)b.y;
    r[6] = (_Float16)b.z; r[7] = (_Float16)b.w;
    return r;
}

__device__ __forceinline__ float tanh_fast(float x) {
    float ax = __builtin_fabsf(x);
    ax = fminf(ax, 15.f);
    float e = __expf(2.f * ax);
    float t = 1.f - 2.f * __builtin_amdgcn_rcpf(e + 1.f);
    return (x < 0.f) ? -t : t;
}

/* async global->LDS, 16B/lane; LDS dest = wave-uniform base + lane*16 */
__device__ __forceinline__ void glds16(const void* g, void* l) {
    __builtin_amdgcn_global_load_lds((const __attribute__((address_space(1))) uint32_t*)g,
                                     (__attribute__((address_space(3))) uint32_t*)l,
                                     16, 0, 0);
}

/* ---- ws layouts (bytes) ---- */
#define OFF_WENCT 0
#define OFF_WATTT 1048576
#define OFF_CONV  1081344
#define M_DTERM   5177344
#define M_EPART   5242880
#define M_CPART   6266880
#define M_ENCH    8364032
#define F_DTERM   9273344
#define F_EPART   9338880
#define F_CPART   10362880

/* ---- fused prep: [0,512) We transpose, [512,640) dterm, [640,1152) conv,
 *      [1152] Wat, [1153, 1153+8000) enc->f16 conversion (8192 elems/blk, main) */
__global__ __launch_bounds__(256) void k_prep(const float* __restrict__ We,
                                              const float* __restrict__ Wa,
                                              const float* __restrict__ dec_h,
                                              const float* __restrict__ W_dec,
                                              const float* __restrict__ be,
                                              const float* __restrict__ bd,
                                              const float* __restrict__ ba,
                                              const float* __restrict__ att_prev,
                                              const float* __restrict__ conv_w,
                                              const float* __restrict__ enc,
                                              _Float16* __restrict__ Wet,
                                              _Float16* __restrict__ Wat,
                                              float* __restrict__ dterm,
                                              void* __restrict__ convO,
                                              _Float16* __restrict__ encH,
                                              int f16mode) {
    __shared__ float smem[3460];
    const int blk = blockIdx.x, tid = threadIdx.x;

    if (blk >= 1153) {
        /* enc fp32 -> f16, 8192 elems/block */
        const size_t base = (size_t)(blk - 1153) * 8192 + (size_t)tid * 8;
#pragma unroll
        for (int i = 0; i < 4; ++i) {
            const size_t idx = base + (size_t)i * 2048;
            const float4_t* s = (const float4_t*)(enc + idx);
            *(half8_t*)(encH + idx) = pack8(s[0], s[1]);
        }
        return;
    }
    if (blk < 512) {
        float (*tile)[33] = (float(*)[33])smem;
        const int k0 = (blk >> 4) * 32, n0 = (blk & 15) * 32;
        const int tx = tid & 31, ty = tid >> 5;
#pragma unroll
        for (int i = 0; i < 4; ++i)
            tile[ty + i * 8][tx] = We[(size_t)(k0 + ty + i * 8) * ADIM + n0 + tx];
        __syncthreads();
#pragma unroll
        for (int i = 0; i < 4; ++i)
            Wet[(size_t)(n0 + ty + i * 8) * KDIM + k0 + tx] = (_Float16)tile[tx][ty + i * 8];
    } else if (blk < 640) {
        float* dh = smem;
        float* part = smem + 1024;
        const int idx = blk - 512, b = idx >> 2, a0 = (idx & 3) * 128;
#pragma unroll
        for (int i = 0; i < 4; ++i) dh[tid + i * 256] = dec_h[b * KDIM + tid + i * 256];
        __syncthreads();
        const int a = a0 + (tid & 127), kh = (tid >> 7) * 512;
        float s = 0.f;
#pragma unroll 8
        for (int k = 0; k < 512; ++k) s += dh[kh + k] * W_dec[(size_t)(kh + k) * ADIM + a];
        part[tid] = s;
        __syncthreads();
        if (tid < 128) {
            const int aa = a0 + tid;
            dterm[b * ADIM + aa] = part[tid] + part[tid + 128] + be[aa] + bd[aa] + ba[aa];
        }
    } else if (blk < 1152) {
        float* ap = smem;
        float* w  = smem + 228;
        const int idx = blk - 640, b = idx >> 4, tt = idx & 15;
        const int t0 = tt * 128;
        for (int i = tid; i < 228; i += 256) {
            int t = t0 - 50 + i;
            ap[i] = (t >= 0 && t < T_LEN) ? att_prev[b * T_LEN + t] : 0.f;
        }
        for (int i = tid; i < CCH * KW; i += 256) w[i] = conv_w[i];
        __syncthreads();
        for (int idx2 = tid; idx2 < 128 * CCH; idx2 += 256) {
            int tl = idx2 >> 5, c = idx2 & 31;
            int t = t0 + tl;
            if (t < T_LEN) {
                float s = 0.f;
#pragma unroll
                for (int j = 0; j < KW; ++j) s += ap[tl + j] * w[c * KW + j];
                const size_t o = (size_t)(b * T_LEN + t) * CCH + c;
                if (f16mode) ((_Float16*)convO)[o] = (_Float16)s;
                else         ((float*)convO)[o] = s;
            }
        }
    } else {
#pragma unroll
        for (int rr = 0; rr < 2; ++rr) {
            const int n = tid * 2 + rr;
#pragma unroll
            for (int c = 0; c < CCH; ++c)
                Wat[n * CCH + c] = (_Float16)Wa[c * ADIM + n];
        }
    }
}

/* =====================================================================
 * Main-path fused GEMM+tanh+dot — the proven round-0 structure.
 * 2000 blocks (XCD-swizzled: 4 nc-siblings of an m-tile on one XCD),
 * 256 thr = 4 waves, tile 128x128, wave 64x64, BK=32, 2-buffer drain
 * schedule, 32KB LDS.
 * ONLY change vs the 612us version: __launch_bounds__(256,5) -> 5
 * blocks/CU (LDS 160/32=5; VGPR budget 512/5=102 >= 68 measured -> no
 * spill). Occupancy 16 -> 20 waves/CU.
 * ===================================================================== */
__global__ __launch_bounds__(256, 5)
void k_gemm_e5(const _Float16* __restrict__ encH,
               const _Float16* __restrict__ Wet,
               const _Float16* __restrict__ cvH,
               const _Float16* __restrict__ Wat,
               const float* __restrict__ dterm,
               const float* __restrict__ gvec,
               float* __restrict__ epart) {
    __shared__ __attribute__((aligned(16))) char     Ab[2][8192];
    __shared__ __attribute__((aligned(16))) _Float16 Bh[2][4096];

    const int tid  = threadIdx.x;
    const int blk  = blockIdx.x;
    int nc, mt;
    if (blk < 1984) { nc = (blk >> 3) & 3; mt = (blk >> 5) * 8 + (blk & 7); }
    else            { int r = blk - 1984; nc = r >> 2; mt = 496 + (r & 3); }
    const int m0 = mt * 128, n0 = nc * 128;

    const int wave = tid >> 6, lane = tid & 63;
    const int quad = lane >> 4, c16 = lane & 15;
    const int wm = (wave >> 1) * 64, wn = (wave & 1) * 64;
    const int rl = lane & 15, sg = lane >> 4;   /* seg-major 16B staging lanes */

    const size_t aRow = (size_t)(m0 + wave * 32 + rl);
    const size_t bRow = (size_t)(n0 + wave * 32 + rl);

    /* epilogue data */
    float g[4], dt0[4], dt1[4];
    const int b0 = m0 / T_LEN, b1 = (m0 + 127) / T_LEN;
    const int lim = (b0 + 1) * T_LEN;
#pragma unroll
    for (int j = 0; j < 4; ++j) {
        const int col = n0 + wn + j * 16 + c16;
        g[j]   = gvec[col];
        dt0[j] = dterm[b0 * ADIM + col];
        dt1[j] = dterm[b1 * ADIM + col];
    }

    float4_t acc[4][4];
#pragma unroll
    for (int i = 0; i < 4; ++i)
#pragma unroll
        for (int j = 0; j < 4; ++j) acc[i][j] = (float4_t){0.f, 0.f, 0.f, 0.f};

#define STAGE_A(buf, base, stride, k0)                                              \
    _Pragma("unroll")                                                               \
    for (int i = 0; i < 2; ++i)                                                     \
        glds16((base) + ((aRow + i * 16) * (stride)) + (k0) + sg * 8,               \
               &Ab[buf][(wave * 2 + i) * 1024]);
#define STAGE_B(buf, base, stride, k0)                                              \
    _Pragma("unroll")                                                               \
    for (int i = 0; i < 2; ++i)                                                     \
        glds16((base) + ((bRow + i * 16) * (stride)) + (k0) + sg * 8,               \
               (char*)&Bh[buf][0] + (wave * 2 + i) * 1024);

    /* prologue: stage K-step 0 into buf 0 */
    STAGE_A(0, encH, KDIM, 0)
    STAGE_B(0, Wet, KDIM, 0)
    __syncthreads();

    for (int kk = 0; kk < 33; ++kk) {
        const int cur = kk & 1, nxt = cur ^ 1;
        if (kk < 31) {
            const int kn = (kk + 1) * 32;
            STAGE_A(nxt, encH, KDIM, kn)
            STAGE_B(nxt, Wet, KDIM, kn)
        } else if (kk == 31) {   /* conv K-step */
            STAGE_A(nxt, cvH, CCH, 0)
            STAGE_B(nxt, Wat, CCH, 0)
        }
        half8_t af[4], bf4[4];
        const _Float16* Ah = (const _Float16*)Ab[cur];
        const _Float16* Bp = &Bh[cur][0];
#pragma unroll
        for (int i = 0; i < 4; ++i) {
            const int row = wm + i * 16 + c16;
            af[i] = *(const half8_t*)(Ah + (row >> 4) * 512 + (quad * 16 + c16) * 8);
        }
#pragma unroll
        for (int j = 0; j < 4; ++j) {
            const int row = wn + j * 16 + c16;
            bf4[j] = *(const half8_t*)(Bp + (row >> 4) * 512 + (quad * 16 + c16) * 8);
        }
#pragma unroll
        for (int i = 0; i < 4; ++i)
#pragma unroll
            for (int j = 0; j < 4; ++j)
                acc[i][j] = __builtin_amdgcn_mfma_f32_16x16x32_f16(af[i], bf4[j], acc[i][j], 0, 0, 0);
        __syncthreads();
    }
#undef STAGE_A
#undef STAGE_B

    /* epilogue: + dterm, tanh, *g, 16-lane reduce, combine 2 n-waves */
    float* e_lds = (float*)&Bh[0][0];   /* [128][2] floats */
#pragma unroll
    for (int i = 0; i < 4; ++i) {
#pragma unroll
        for (int r = 0; r < 4; ++r) {
            const int rloc = wm + i * 16 + quad * 4 + r;
            const bool hi = (m0 + rloc) >= lim;
            float s = 0.f;
#pragma unroll
            for (int j = 0; j < 4; ++j)
                s += tanh_fast(acc[i][j][r] + (hi ? dt1[j] : dt0[j])) * g[j];
#pragma unroll
            for (int off = 1; off < 16; off <<= 1) s += __shfl_xor(s, off);
            if (c16 == 0) e_lds[rloc * 2 + (wave & 1)] = s;
        }
    }
    __syncthreads();
    if (tid < 128) {
        const float2 q = ((const float2*)e_lds)[tid];
        epart[nc * ROWS + m0 + tid] = q.x + q.y;
    }
}

/* fallback-path GEMM (fp32 A), original 2-buffer structure, 4 nc-planes */
__global__ __launch_bounds__(256, 3)
void k_gemm_f(const float* __restrict__ encF,
              const _Float16* __restrict__ Wet,
              const float* __restrict__ cvF,
              const _Float16* __restrict__ Wat,
              const float* __restrict__ dterm,
              const float* __restrict__ gvec,
              float* __restrict__ epart) {
    __shared__ __attribute__((aligned(16))) char     Ab[2][16384];
    __shared__ __attribute__((aligned(16))) _Float16 Bh[2][128 * 32];

    const int tid  = threadIdx.x;
    const int blk  = blockIdx.x;
    int nc, mt;
    if (blk < 1984) { nc = (blk >> 3) & 3; mt = (blk >> 5) * 8 + (blk & 7); }
    else            { int r = blk - 1984; nc = r >> 2; mt = 496 + (r & 3); }
    const int m0 = mt * 128, n0 = nc * 128;

    const int wave = tid >> 6, lane = tid & 63;
    const int quad = lane >> 4, c16 = lane & 15;
    const int wm = (wave >> 1) * 64, wn = (wave & 1) * 64;

    const int rlB = lane & 15, sgB = lane >> 4;
    const int rlA = lane & 7,  sgA = lane >> 3;

    const size_t aRow = (size_t)(m0 + wave * 32 + rlA);
    const size_t bRow = (size_t)(n0 + wave * 32 + rlB);

    float g[4], dt0[4], dt1[4];
    const int b0 = m0 / T_LEN, b1 = (m0 + 127) / T_LEN;
    const int lim = (b0 + 1) * T_LEN;
#pragma unroll
    for (int j = 0; j < 4; ++j) {
        const int col = n0 + wn + j * 16 + c16;
        g[j]   = gvec[col];
        dt0[j] = dterm[b0 * ADIM + col];
        dt1[j] = dterm[b1 * ADIM + col];
    }

    float4_t acc[4][4];
#pragma unroll
    for (int i = 0; i < 4; ++i)
#pragma unroll
        for (int j = 0; j < 4; ++j) acc[i][j] = (float4_t){0.f, 0.f, 0.f, 0.f};

#define STAGE_A(buf, base, stride, k0)                                              \
    _Pragma("unroll")                                                               \
    for (int i = 0; i < 4; ++i)                                                     \
        glds16((base) + ((aRow + i * 8) * (stride)) + (k0) + sgA * 4,               \
               &Ab[buf][(wave * 4 + i) * 1024]);
#define STAGE_B(buf, base, stride, k0)                                              \
    _Pragma("unroll")                                                               \
    for (int i = 0; i < 2; ++i)                                                     \
        glds16((base) + ((bRow + i * 16) * (stride)) + (k0) + sgB * 8,              \
               (char*)&Bh[buf][0] + (wave * 2 + i) * 1024);

    STAGE_A(0, encF, KDIM, 0)
    STAGE_B(0, Wet, KDIM, 0)
    __syncthreads();

    for (int kk = 0; kk < 33; ++kk) {
        const int cur = kk & 1, nxt = cur ^ 1;
        if (kk < 31) {
            const int kn = (kk + 1) * 32;
            STAGE_A(nxt, encF, KDIM, kn)
            STAGE_B(nxt, Wet, KDIM, kn)
        } else if (kk == 31) {
            STAGE_A(nxt, cvF, CCH, 0)
            STAGE_B(nxt, Wat, CCH, 0)
        }
        half8_t af[4], bf[4];
        const float* Afp = (const float*)Ab[cur];
#pragma unroll
        for (int i = 0; i < 4; ++i) {
            const int row = wm + i * 16 + c16;
            const float* cb = Afp + (row >> 3) * 256 + (row & 7) * 4;
            float4_t u0 = *(const float4_t*)(cb + (2 * quad) * 32);
            float4_t u1 = *(const float4_t*)(cb + (2 * quad + 1) * 32);
            af[i] = pack8(u0, u1);
        }
#pragma unroll
        for (int j = 0; j < 4; ++j) {
            const int row = wn + j * 16 + c16;
            bf[j] = *(const half8_t*)(&Bh[cur][0] + (row >> 4) * 512 + (quad * 16 + c16) * 8);
        }
#pragma unroll
        for (int i = 0; i < 4; ++i)
#pragma unroll
            for (int j = 0; j < 4; ++j)
                acc[i][j] = __builtin_amdgcn_mfma_f32_16x16x32_f16(af[i], bf[j], acc[i][j], 0, 0, 0);
        __syncthreads();
    }
#undef STAGE_A
#undef STAGE_B

    float* e_lds = (float*)&Bh[0][0];
#pragma unroll
    for (int i = 0; i < 4; ++i) {
#pragma unroll
        for (int r = 0; r < 4; ++r) {
            const int rloc = wm + i * 16 + quad * 4 + r;
            const bool hi = (m0 + rloc) >= lim;
            float s = 0.f;
#pragma unroll
            for (int j = 0; j < 4; ++j)
                s += tanh_fast(acc[i][j][r] + (hi ? dt1[j] : dt0[j])) * g[j];
#pragma unroll
            for (int off = 1; off < 16; off <<= 1) s += __shfl_xor(s, off);
            if (c16 == 0) e_lds[rloc * 2 + (wave & 1)] = s;
        }
    }
    __syncthreads();
    if (tid < 128) {
        const float2 q = ((const float2*)e_lds)[tid];
        epart[nc * ROWS + m0 + tid] = q.x + q.y;
    }
}

/* softmax over T; logit = 2*sum_{p<np} epart[p], masked -> -2e15 */
__global__ __launch_bounds__(512) void k_softmax(const float* __restrict__ epart,
                                                 const int* __restrict__ enc_len,
                                                 float* __restrict__ attn,
                                                 int np) {
    __shared__ float ex[T_LEN];
    __shared__ float red[8];
    const int b = blockIdx.x, tid = threadIdx.x;
    const int len = enc_len[b];
    float lmax = -3.4e38f;
    for (int t = tid; t < T_LEN; t += 512) {
        float e = epart[b * T_LEN + t];
        for (int p = 1; p < np; ++p) e += epart[p * ROWS + b * T_LEN + t];
        float lg = (t < len) ? 2.f * e : -2e15f;
        ex[t] = lg;
        lmax = fmaxf(lmax, lg);
    }
    for (int off = 1; off < 64; off <<= 1) lmax = fmaxf(lmax, __shfl_xor(lmax, off));
    if ((tid & 63) == 0) red[tid >> 6] = lmax;
    __syncthreads();
    const float m = fmaxf(fmaxf(fmaxf(red[0], red[1]), fmaxf(red[2], red[3])),
                          fmaxf(fmaxf(red[4], red[5]), fmaxf(red[6], red[7])));
    float lsum = 0.f;
    for (int t = tid; t < T_LEN; t += 512) {
        float p = __expf(ex[t] - m);
        ex[t] = p;
        lsum += p;
    }
    for (int off = 1; off < 64; off <<= 1) lsum += __shfl_xor(lsum, off);
    __syncthreads();
    if ((tid & 63) == 0) red[tid >> 6] = lsum;
    __syncthreads();
    const float inv = 1.f / (red[0] + red[1] + red[2] + red[3] + red[4] + red[5] + red[6] + red[7]);
    for (int t = tid; t < T_LEN; t += 512) attn[b * T_LEN + t] = ex[t] * inv;
}

/* c partial from f16 enc copy */
__global__ __launch_bounds__(256) void k_cpart_h(const float* __restrict__ attn,
                                                 const _Float16* __restrict__ encH,
                                                 float* __restrict__ cpart) {
    const int b = blockIdx.y, tc = blockIdx.x, tid = threadIdx.x;
    const int t0 = tc * 125;
    float4_t s = (float4_t){0.f, 0.f, 0.f, 0.f};
    const half4_t* ep = (const half4_t*)(encH + (size_t)b * T_LEN * KDIM) + tid;
    const float* ap = attn + b * T_LEN + t0;
#pragma unroll 5
    for (int tt = 0; tt < 125; ++tt) {
        const float w = ap[tt];
        half4_t v = ep[(size_t)(t0 + tt) * 256];
        s.x += w * (float)v[0]; s.y += w * (float)v[1];
        s.z += w * (float)v[2]; s.w += w * (float)v[3];
    }
    *(float4_t*)&cpart[(size_t)(tc * BATCH + b) * KDIM + tid * 4] = s;
}

/* c partial from fp32 enc (fallback) */
__global__ __launch_bounds__(256) void k_cpart_f(const float* __restrict__ attn,
                                                 const float* __restrict__ enc,
                                                 float* __restrict__ cpart) {
    const int b = blockIdx.y, tc = blockIdx.x, tid = threadIdx.x;
    const int t0 = tc * 125;
    float4_t s = (float4_t){0.f, 0.f, 0.f, 0.f};
    const float4_t* ep = (const float4_t*)(enc + (size_t)b * T_LEN * KDIM) + tid;
    const float* ap = attn + b * T_LEN + t0;
#pragma unroll 5
    for (int tt = 0; tt < 125; ++tt) {
        const float w = ap[tt];
        float4_t v = ep[(size_t)(t0 + tt) * 256];
        s += v * w;
    }
    *(float4_t*)&cpart[(size_t)(tc * BATCH + b) * KDIM + tid * 4] = s;
}

/* out_c[b][o] = b_o[o] + sum_d (sum_p cpart[p][b][d]) * W_o[d][o] ; grid (32,4) x 256 */
__global__ __launch_bounds__(256) void k_out(const float* __restrict__ cpart,
                                             const float* __restrict__ W_o,
                                             const float* __restrict__ b_o,
                                             float* __restrict__ out_c) {
    __shared__ float cm[KDIM];
    const int b = blockIdx.x, tid = threadIdx.x;
    for (int d = tid; d < KDIM; d += 256) {
        float s = 0.f;
#pragma unroll
        for (int p = 0; p < 16; ++p) s += cpart[(size_t)(p * BATCH + b) * KDIM + d];
        cm[d] = s;
    }
    __syncthreads();
    const int o = blockIdx.y * 256 + tid;
    float s = b_o[o];
#pragma unroll 8
    for (int d = 0; d < KDIM; ++d) s += cm[d] * W_o[(size_t)d * KDIM + o];
    out_c[b * KDIM + o] = s;
}

extern "C" void kernel_launch(void* const* d_in, const int* in_sizes, int n_in,
                              void* d_out, int out_size, void* d_ws, size_t ws_size,
                              hipStream_t stream) {
    const float* enc      = (const float*)d_in[0];
    const int*   enc_len  = (const int*)d_in[1];
    const float* dec_h    = (const float*)d_in[2];
    const float* att_prev = (const float*)d_in[3];
    const float* W_enc    = (const float*)d_in[4];
    const float* b_enc    = (const float*)d_in[5];
    const float* W_dec    = (const float*)d_in[6];
    const float* b_dec    = (const float*)d_in[7];
    const float* W_att    = (const float*)d_in[8];
    const float* b_att    = (const float*)d_in[9];
    const float* conv_w   = (const float*)d_in[10];
    const float* gvec     = (const float*)d_in[11];
    const float* W_o      = (const float*)d_in[12];
    const float* b_o      = (const float*)d_in[13];

    float* out_c    = (float*)d_out;           /* 32*1024 */
    float* out_attn = out_c + BATCH * KDIM;    /* 32*2000 */

    char* ws = (char*)d_ws;
    _Float16* Wet = (_Float16*)(ws + OFF_WENCT);
    _Float16* Wat = (_Float16*)(ws + OFF_WATTT);

    const size_t needMain = (size_t)M_ENCH + (size_t)ROWS * KDIM * 2;
    const bool f16p = ws_size >= needMain;

    if (f16p) {
        _Float16* convH = (_Float16*)(ws + OFF_CONV);
        float*    dterm = (float*)(ws + M_DTERM);
        float*    epart = (float*)(ws + M_EPART);
        float*    cpart = (float*)(ws + M_CPART);
        _Float16* encH  = (_Float16*)(ws + M_ENCH);

        k_prep<<<1153 + 8000, 256, 0, stream>>>(W_enc, W_att, dec_h, W_dec, b_enc, b_dec,
                                                b_att, att_prev, conv_w, enc,
                                                Wet, Wat, dterm, convH, encH, 1);
        k_gemm_e5<<<2000, 256, 0, stream>>>(encH, Wet, convH, Wat, dterm, gvec, epart);
        k_softmax<<<BATCH, 512, 0, stream>>>(epart, enc_len, out_attn, 4);
        k_cpart_h<<<dim3(16, BATCH), 256, 0, stream>>>(out_attn, encH, cpart);
        k_out<<<dim3(BATCH, 4), 256, 0, stream>>>(cpart, W_o, b_o, out_c);
    } else {
        float* convF = (float*)(ws + OFF_CONV);
        float* dterm = (float*)(ws + F_DTERM);
        float* epart = (float*)(ws + F_EPART);
        float* cpart = (float*)(ws + F_CPART);

        k_prep<<<1153, 256, 0, stream>>>(W_enc, W_att, dec_h, W_dec, b_enc, b_dec,
                                         b_att, att_prev, conv_w, enc,
                                         Wet, Wat, dterm, convF, (_Float16*)nullptr, 0);
        k_gemm_f<<<2000, 256, 0, stream>>>(enc, Wet, convF, Wat, dterm, gvec, epart);
        k_softmax<<<BATCH, 512, 0, stream>>>(epart, enc_len, out_attn, 4);
        k_cpart_f<<<dim3(16, BATCH), 256, 0, stream>>>(out_attn, enc, cpart);
        k_out<<<dim3(BATCH, 4), 256, 0, stream>>>(cpart, W_o, b_o, out_c);
    }
}

// Round 5
// 658.883 us; speedup vs baseline: 1.4493x; 1.0395x over previous
//
#include <hip/hip_runtime.h>
#include <stdint.h>
#include <stddef.h>

#define T_LEN   2000
#define BATCH   32
#define ROWS    64000      /* B*T */
#define KDIM    1024
#define ADIM    512
#define CCH     32
#define KW      101        /* 2*50+1 */

typedef _Float16 half8_t  __attribute__((ext_vector_type(8)));
typedef _Float16 half4_t  __attribute__((ext_vector_type(4)));
typedef float    float4_t __attribute__((ext_vector_type(4)));

__device__ __forceinline__ half8_t pack8(float4_t a, float4_t b) {
    half8_t r;
    r[0] = (_Float16)a.x; r[1] = (_Float16)a.y;
    r[2] = (_Float16)a.z; r[3] = (_Float16)a.w;
    r[4] = (_Float16)b.x; r[5] = (_Float16)b.y;
    r[6] = (_Float16)b.z; r[7] = (_Float16)b.w;
    return r;
}

__device__ __forceinline__ float tanh_fast(float x) {
    float ax = __builtin_fabsf(x);
    ax = fminf(ax, 15.f);
    float e = __expf(2.f * ax);
    float t = 1.f - 2.f * __builtin_amdgcn_rcpf(e + 1.f);
    return (x < 0.f) ? -t : t;
}

/* async global->LDS, 16B/lane; LDS dest = wave-uniform base + lane*16 */
__device__ __forceinline__ void glds16(const void* g, void* l) {
    __builtin_amdgcn_global_load_lds((const __attribute__((address_space(1))) uint32_t*)g,
                                     (__attribute__((address_space(3))) uint32_t*)l,
                                     16, 0, 0);
}

/* ---- ws layouts (bytes) ----
 * main: WENCT 0 | WATTT 1048576 | CONVH 1081344 | DTERM 5177344 |
 *       EPART 5242880 (4 planes) | CPART 6266880 (40 planes, 5.24MB) |
 *       ENCH 11509760 (131MB)  — ws is ~1GiB, ample.
 * fallback: CONVF f32 -> DTERM 9273344, EPART 9338880, CPART 10362880 (16pl) */
#define OFF_WENCT 0
#define OFF_WATTT 1048576
#define OFF_CONV  1081344
#define M_DTERM   5177344
#define M_EPART   5242880
#define M_CPART   6266880
#define M_ENCH    11509760
#define F_DTERM   9273344
#define F_EPART   9338880
#define F_CPART   10362880

/* ---- fused prep: [0,512) We transpose, [512,640) dterm, [640,1152) conv,
 *      [1152] Wat, [1153, 1153+8000) enc->f16 conversion (8192 elems/blk, main) */
__global__ __launch_bounds__(256) void k_prep(const float* __restrict__ We,
                                              const float* __restrict__ Wa,
                                              const float* __restrict__ dec_h,
                                              const float* __restrict__ W_dec,
                                              const float* __restrict__ be,
                                              const float* __restrict__ bd,
                                              const float* __restrict__ ba,
                                              const float* __restrict__ att_prev,
                                              const float* __restrict__ conv_w,
                                              const float* __restrict__ enc,
                                              _Float16* __restrict__ Wet,
                                              _Float16* __restrict__ Wat,
                                              float* __restrict__ dterm,
                                              void* __restrict__ convO,
                                              _Float16* __restrict__ encH,
                                              int f16mode) {
    __shared__ float smem[3460];
    const int blk = blockIdx.x, tid = threadIdx.x;

    if (blk >= 1153) {
        /* enc fp32 -> f16, 8192 elems/block */
        const size_t base = (size_t)(blk - 1153) * 8192 + (size_t)tid * 8;
#pragma unroll
        for (int i = 0; i < 4; ++i) {
            const size_t idx = base + (size_t)i * 2048;
            const float4_t* s = (const float4_t*)(enc + idx);
            *(half8_t*)(encH + idx) = pack8(s[0], s[1]);
        }
        return;
    }
    if (blk < 512) {
        float (*tile)[33] = (float(*)[33])smem;
        const int k0 = (blk >> 4) * 32, n0 = (blk & 15) * 32;
        const int tx = tid & 31, ty = tid >> 5;
#pragma unroll
        for (int i = 0; i < 4; ++i)
            tile[ty + i * 8][tx] = We[(size_t)(k0 + ty + i * 8) * ADIM + n0 + tx];
        __syncthreads();
#pragma unroll
        for (int i = 0; i < 4; ++i)
            Wet[(size_t)(n0 + ty + i * 8) * KDIM + k0 + tx] = (_Float16)tile[tx][ty + i * 8];
    } else if (blk < 640) {
        float* dh = smem;
        float* part = smem + 1024;
        const int idx = blk - 512, b = idx >> 2, a0 = (idx & 3) * 128;
#pragma unroll
        for (int i = 0; i < 4; ++i) dh[tid + i * 256] = dec_h[b * KDIM + tid + i * 256];
        __syncthreads();
        const int a = a0 + (tid & 127), kh = (tid >> 7) * 512;
        float s = 0.f;
#pragma unroll 8
        for (int k = 0; k < 512; ++k) s += dh[kh + k] * W_dec[(size_t)(kh + k) * ADIM + a];
        part[tid] = s;
        __syncthreads();
        if (tid < 128) {
            const int aa = a0 + tid;
            dterm[b * ADIM + aa] = part[tid] + part[tid + 128] + be[aa] + bd[aa] + ba[aa];
        }
    } else if (blk < 1152) {
        float* ap = smem;
        float* w  = smem + 228;
        const int idx = blk - 640, b = idx >> 4, tt = idx & 15;
        const int t0 = tt * 128;
        for (int i = tid; i < 228; i += 256) {
            int t = t0 - 50 + i;
            ap[i] = (t >= 0 && t < T_LEN) ? att_prev[b * T_LEN + t] : 0.f;
        }
        for (int i = tid; i < CCH * KW; i += 256) w[i] = conv_w[i];
        __syncthreads();
        for (int idx2 = tid; idx2 < 128 * CCH; idx2 += 256) {
            int tl = idx2 >> 5, c = idx2 & 31;
            int t = t0 + tl;
            if (t < T_LEN) {
                float s = 0.f;
#pragma unroll
                for (int j = 0; j < KW; ++j) s += ap[tl + j] * w[c * KW + j];
                const size_t o = (size_t)(b * T_LEN + t) * CCH + c;
                if (f16mode) ((_Float16*)convO)[o] = (_Float16)s;
                else         ((float*)convO)[o] = s;
            }
        }
    } else {
#pragma unroll
        for (int rr = 0; rr < 2; ++rr) {
            const int n = tid * 2 + rr;
#pragma unroll
            for (int c = 0; c < CCH; ++c)
                Wat[n * CCH + c] = (_Float16)Wa[c * ADIM + n];
        }
    }
}

/* =====================================================================
 * Main-path fused GEMM+tanh+dot — EXACT round-0 proven structure.
 * 2000 blocks (XCD-swizzled), 256 thr = 4 waves, tile 128x128, wave
 * 64x64, BK=32, 2-buffer drain schedule, 32KB LDS, launch_bounds(256,4).
 * NOTE: acc = 64 AGPR + ~68 arch VGPR ≈ 132 regs/wave -> 4 waves/SIMD is
 * the register ceiling; bounds >4 forced spills (rounds 3/4 regressions).
 * ===================================================================== */
__global__ __launch_bounds__(256, 4)
void k_gemm_e4(const _Float16* __restrict__ encH,
               const _Float16* __restrict__ Wet,
               const _Float16* __restrict__ cvH,
               const _Float16* __restrict__ Wat,
               const float* __restrict__ dterm,
               const float* __restrict__ gvec,
               float* __restrict__ epart) {
    __shared__ __attribute__((aligned(16))) char     Ab[2][8192];
    __shared__ __attribute__((aligned(16))) _Float16 Bh[2][4096];

    const int tid  = threadIdx.x;
    const int blk  = blockIdx.x;
    int nc, mt;
    if (blk < 1984) { nc = (blk >> 3) & 3; mt = (blk >> 5) * 8 + (blk & 7); }
    else            { int r = blk - 1984; nc = r >> 2; mt = 496 + (r & 3); }
    const int m0 = mt * 128, n0 = nc * 128;

    const int wave = tid >> 6, lane = tid & 63;
    const int quad = lane >> 4, c16 = lane & 15;
    const int wm = (wave >> 1) * 64, wn = (wave & 1) * 64;
    const int rl = lane & 15, sg = lane >> 4;   /* seg-major 16B staging lanes */

    const size_t aRow = (size_t)(m0 + wave * 32 + rl);
    const size_t bRow = (size_t)(n0 + wave * 32 + rl);

    /* epilogue data */
    float g[4], dt0[4], dt1[4];
    const int b0 = m0 / T_LEN, b1 = (m0 + 127) / T_LEN;
    const int lim = (b0 + 1) * T_LEN;
#pragma unroll
    for (int j = 0; j < 4; ++j) {
        const int col = n0 + wn + j * 16 + c16;
        g[j]   = gvec[col];
        dt0[j] = dterm[b0 * ADIM + col];
        dt1[j] = dterm[b1 * ADIM + col];
    }

    float4_t acc[4][4];
#pragma unroll
    for (int i = 0; i < 4; ++i)
#pragma unroll
        for (int j = 0; j < 4; ++j) acc[i][j] = (float4_t){0.f, 0.f, 0.f, 0.f};

#define STAGE_A(buf, base, stride, k0)                                              \
    _Pragma("unroll")                                                               \
    for (int i = 0; i < 2; ++i)                                                     \
        glds16((base) + ((aRow + i * 16) * (stride)) + (k0) + sg * 8,               \
               &Ab[buf][(wave * 2 + i) * 1024]);
#define STAGE_B(buf, base, stride, k0)                                              \
    _Pragma("unroll")                                                               \
    for (int i = 0; i < 2; ++i)                                                     \
        glds16((base) + ((bRow + i * 16) * (stride)) + (k0) + sg * 8,               \
               (char*)&Bh[buf][0] + (wave * 2 + i) * 1024);

    /* prologue: stage K-step 0 into buf 0 */
    STAGE_A(0, encH, KDIM, 0)
    STAGE_B(0, Wet, KDIM, 0)
    __syncthreads();

    for (int kk = 0; kk < 33; ++kk) {
        const int cur = kk & 1, nxt = cur ^ 1;
        if (kk < 31) {
            const int kn = (kk + 1) * 32;
            STAGE_A(nxt, encH, KDIM, kn)
            STAGE_B(nxt, Wet, KDIM, kn)
        } else if (kk == 31) {   /* conv K-step */
            STAGE_A(nxt, cvH, CCH, 0)
            STAGE_B(nxt, Wat, CCH, 0)
        }
        half8_t af[4], bf4[4];
        const _Float16* Ah = (const _Float16*)Ab[cur];
        const _Float16* Bp = &Bh[cur][0];
#pragma unroll
        for (int i = 0; i < 4; ++i) {
            const int row = wm + i * 16 + c16;
            af[i] = *(const half8_t*)(Ah + (row >> 4) * 512 + (quad * 16 + c16) * 8);
        }
#pragma unroll
        for (int j = 0; j < 4; ++j) {
            const int row = wn + j * 16 + c16;
            bf4[j] = *(const half8_t*)(Bp + (row >> 4) * 512 + (quad * 16 + c16) * 8);
        }
#pragma unroll
        for (int i = 0; i < 4; ++i)
#pragma unroll
            for (int j = 0; j < 4; ++j)
                acc[i][j] = __builtin_amdgcn_mfma_f32_16x16x32_f16(af[i], bf4[j], acc[i][j], 0, 0, 0);
        __syncthreads();
    }
#undef STAGE_A
#undef STAGE_B

    /* epilogue: + dterm, tanh, *g, 16-lane reduce, combine 2 n-waves */
    float* e_lds = (float*)&Bh[0][0];   /* [128][2] floats */
#pragma unroll
    for (int i = 0; i < 4; ++i) {
#pragma unroll
        for (int r = 0; r < 4; ++r) {
            const int rloc = wm + i * 16 + quad * 4 + r;
            const bool hi = (m0 + rloc) >= lim;
            float s = 0.f;
#pragma unroll
            for (int j = 0; j < 4; ++j)
                s += tanh_fast(acc[i][j][r] + (hi ? dt1[j] : dt0[j])) * g[j];
#pragma unroll
            for (int off = 1; off < 16; off <<= 1) s += __shfl_xor(s, off);
            if (c16 == 0) e_lds[rloc * 2 + (wave & 1)] = s;
        }
    }
    __syncthreads();
    if (tid < 128) {
        const float2 q = ((const float2*)e_lds)[tid];
        epart[nc * ROWS + m0 + tid] = q.x + q.y;
    }
}

/* fallback-path GEMM (fp32 A), original 2-buffer structure, 4 nc-planes */
__global__ __launch_bounds__(256, 3)
void k_gemm_f(const float* __restrict__ encF,
              const _Float16* __restrict__ Wet,
              const float* __restrict__ cvF,
              const _Float16* __restrict__ Wat,
              const float* __restrict__ dterm,
              const float* __restrict__ gvec,
              float* __restrict__ epart) {
    __shared__ __attribute__((aligned(16))) char     Ab[2][16384];
    __shared__ __attribute__((aligned(16))) _Float16 Bh[2][128 * 32];

    const int tid  = threadIdx.x;
    const int blk  = blockIdx.x;
    int nc, mt;
    if (blk < 1984) { nc = (blk >> 3) & 3; mt = (blk >> 5) * 8 + (blk & 7); }
    else            { int r = blk - 1984; nc = r >> 2; mt = 496 + (r & 3); }
    const int m0 = mt * 128, n0 = nc * 128;

    const int wave = tid >> 6, lane = tid & 63;
    const int quad = lane >> 4, c16 = lane & 15;
    const int wm = (wave >> 1) * 64, wn = (wave & 1) * 64;

    const int rlB = lane & 15, sgB = lane >> 4;
    const int rlA = lane & 7,  sgA = lane >> 3;

    const size_t aRow = (size_t)(m0 + wave * 32 + rlA);
    const size_t bRow = (size_t)(n0 + wave * 32 + rlB);

    float g[4], dt0[4], dt1[4];
    const int b0 = m0 / T_LEN, b1 = (m0 + 127) / T_LEN;
    const int lim = (b0 + 1) * T_LEN;
#pragma unroll
    for (int j = 0; j < 4; ++j) {
        const int col = n0 + wn + j * 16 + c16;
        g[j]   = gvec[col];
        dt0[j] = dterm[b0 * ADIM + col];
        dt1[j] = dterm[b1 * ADIM + col];
    }

    float4_t acc[4][4];
#pragma unroll
    for (int i = 0; i < 4; ++i)
#pragma unroll
        for (int j = 0; j < 4; ++j) acc[i][j] = (float4_t){0.f, 0.f, 0.f, 0.f};

#define STAGE_A(buf, base, stride, k0)                                              \
    _Pragma("unroll")                                                               \
    for (int i = 0; i < 4; ++i)                                                     \
        glds16((base) + ((aRow + i * 8) * (stride)) + (k0) + sgA * 4,               \
               &Ab[buf][(wave * 4 + i) * 1024]);
#define STAGE_B(buf, base, stride, k0)                                              \
    _Pragma("unroll")                                                               \
    for (int i = 0; i < 2; ++i)                                                     \
        glds16((base) + ((bRow + i * 16) * (stride)) + (k0) + sgB * 8,              \
               (char*)&Bh[buf][0] + (wave * 2 + i) * 1024);

    STAGE_A(0, encF, KDIM, 0)
    STAGE_B(0, Wet, KDIM, 0)
    __syncthreads();

    for (int kk = 0; kk < 33; ++kk) {
        const int cur = kk & 1, nxt = cur ^ 1;
        if (kk < 31) {
            const int kn = (kk + 1) * 32;
            STAGE_A(nxt, encF, KDIM, kn)
            STAGE_B(nxt, Wet, KDIM, kn)
        } else if (kk == 31) {
            STAGE_A(nxt, cvF, CCH, 0)
            STAGE_B(nxt, Wat, CCH, 0)
        }
        half8_t af[4], bf[4];
        const float* Afp = (const float*)Ab[cur];
#pragma unroll
        for (int i = 0; i < 4; ++i) {
            const int row = wm + i * 16 + c16;
            const float* cb = Afp + (row >> 3) * 256 + (row & 7) * 4;
            float4_t u0 = *(const float4_t*)(cb + (2 * quad) * 32);
            float4_t u1 = *(const float4_t*)(cb + (2 * quad + 1) * 32);
            af[i] = pack8(u0, u1);
        }
#pragma unroll
        for (int j = 0; j < 4; ++j) {
            const int row = wn + j * 16 + c16;
            bf[j] = *(const half8_t*)(&Bh[cur][0] + (row >> 4) * 512 + (quad * 16 + c16) * 8);
        }
#pragma unroll
        for (int i = 0; i < 4; ++i)
#pragma unroll
            for (int j = 0; j < 4; ++j)
                acc[i][j] = __builtin_amdgcn_mfma_f32_16x16x32_f16(af[i], bf[j], acc[i][j], 0, 0, 0);
        __syncthreads();
    }
#undef STAGE_A
#undef STAGE_B

    float* e_lds = (float*)&Bh[0][0];
#pragma unroll
    for (int i = 0; i < 4; ++i) {
#pragma unroll
        for (int r = 0; r < 4; ++r) {
            const int rloc = wm + i * 16 + quad * 4 + r;
            const bool hi = (m0 + rloc) >= lim;
            float s = 0.f;
#pragma unroll
            for (int j = 0; j < 4; ++j)
                s += tanh_fast(acc[i][j][r] + (hi ? dt1[j] : dt0[j])) * g[j];
#pragma unroll
            for (int off = 1; off < 16; off <<= 1) s += __shfl_xor(s, off);
            if (c16 == 0) e_lds[rloc * 2 + (wave & 1)] = s;
        }
    }
    __syncthreads();
    if (tid < 128) {
        const float2 q = ((const float2*)e_lds)[tid];
        epart[nc * ROWS + m0 + tid] = q.x + q.y;
    }
}

/* softmax over T; logit = 2*sum_{p<np} epart[p], masked -> -2e15 */
__global__ __launch_bounds__(512) void k_softmax(const float* __restrict__ epart,
                                                 const int* __restrict__ enc_len,
                                                 float* __restrict__ attn,
                                                 int np) {
    __shared__ float ex[T_LEN];
    __shared__ float red[8];
    const int b = blockIdx.x, tid = threadIdx.x;
    const int len = enc_len[b];
    float lmax = -3.4e38f;
    for (int t = tid; t < T_LEN; t += 512) {
        float e = epart[b * T_LEN + t];
        for (int p = 1; p < np; ++p) e += epart[p * ROWS + b * T_LEN + t];
        float lg = (t < len) ? 2.f * e : -2e15f;
        ex[t] = lg;
        lmax = fmaxf(lmax, lg);
    }
    for (int off = 1; off < 64; off <<= 1) lmax = fmaxf(lmax, __shfl_xor(lmax, off));
    if ((tid & 63) == 0) red[tid >> 6] = lmax;
    __syncthreads();
    const float m = fmaxf(fmaxf(fmaxf(red[0], red[1]), fmaxf(red[2], red[3])),
                          fmaxf(fmaxf(red[4], red[5]), fmaxf(red[6], red[7])));
    float lsum = 0.f;
    for (int t = tid; t < T_LEN; t += 512) {
        float p = __expf(ex[t] - m);
        ex[t] = p;
        lsum += p;
    }
    for (int off = 1; off < 64; off <<= 1) lsum += __shfl_xor(lsum, off);
    __syncthreads();
    if ((tid & 63) == 0) red[tid >> 6] = lsum;
    __syncthreads();
    const float inv = 1.f / (red[0] + red[1] + red[2] + red[3] + red[4] + red[5] + red[6] + red[7]);
    for (int t = tid; t < T_LEN; t += 512) attn[b * T_LEN + t] = ex[t] * inv;
}

/* c partial from f16 enc copy — 40 t-chunks of 50 -> 1280 blocks (5/CU)
 * for latency tolerance on the 131MB stream (was 512 blocks / 8 waves/CU) */
__global__ __launch_bounds__(256) void k_cpart_h(const float* __restrict__ attn,
                                                 const _Float16* __restrict__ encH,
                                                 float* __restrict__ cpart) {
    const int b = blockIdx.y, tc = blockIdx.x, tid = threadIdx.x;
    const int t0 = tc * 50;
    float4_t s = (float4_t){0.f, 0.f, 0.f, 0.f};
    const half4_t* ep = (const half4_t*)(encH + (size_t)b * T_LEN * KDIM) + tid;
    const float* ap = attn + b * T_LEN + t0;
#pragma unroll 10
    for (int tt = 0; tt < 50; ++tt) {
        const float w = ap[tt];
        half4_t v = ep[(size_t)(t0 + tt) * 256];
        s.x += w * (float)v[0]; s.y += w * (float)v[1];
        s.z += w * (float)v[2]; s.w += w * (float)v[3];
    }
    *(float4_t*)&cpart[(size_t)(tc * BATCH + b) * KDIM + tid * 4] = s;
}

/* c partial from fp32 enc (fallback, 16 chunks of 125) */
__global__ __launch_bounds__(256) void k_cpart_f(const float* __restrict__ attn,
                                                 const float* __restrict__ enc,
                                                 float* __restrict__ cpart) {
    const int b = blockIdx.y, tc = blockIdx.x, tid = threadIdx.x;
    const int t0 = tc * 125;
    float4_t s = (float4_t){0.f, 0.f, 0.f, 0.f};
    const float4_t* ep = (const float4_t*)(enc + (size_t)b * T_LEN * KDIM) + tid;
    const float* ap = attn + b * T_LEN + t0;
#pragma unroll 5
    for (int tt = 0; tt < 125; ++tt) {
        const float w = ap[tt];
        float4_t v = ep[(size_t)(t0 + tt) * 256];
        s += v * w;
    }
    *(float4_t*)&cpart[(size_t)(tc * BATCH + b) * KDIM + tid * 4] = s;
}

/* out_c[b][o] = b_o[o] + sum_d (sum_p cpart[p][b][d]) * W_o[d][o] ; grid (32,4) x 256 */
__global__ __launch_bounds__(256) void k_out(const float* __restrict__ cpart,
                                             const float* __restrict__ W_o,
                                             const float* __restrict__ b_o,
                                             float* __restrict__ out_c,
                                             int np) {
    __shared__ float cm[KDIM];
    const int b = blockIdx.x, tid = threadIdx.x;
    for (int d = tid; d < KDIM; d += 256) {
        float s = 0.f;
        for (int p = 0; p < np; ++p) s += cpart[(size_t)(p * BATCH + b) * KDIM + d];
        cm[d] = s;
    }
    __syncthreads();
    const int o = blockIdx.y * 256 + tid;
    float s = b_o[o];
#pragma unroll 8
    for (int d = 0; d < KDIM; ++d) s += cm[d] * W_o[(size_t)d * KDIM + o];
    out_c[b * KDIM + o] = s;
}

extern "C" void kernel_launch(void* const* d_in, const int* in_sizes, int n_in,
                              void* d_out, int out_size, void* d_ws, size_t ws_size,
                              hipStream_t stream) {
    const float* enc      = (const float*)d_in[0];
    const int*   enc_len  = (const int*)d_in[1];
    const float* dec_h    = (const float*)d_in[2];
    const float* att_prev = (const float*)d_in[3];
    const float* W_enc    = (const float*)d_in[4];
    const float* b_enc    = (const float*)d_in[5];
    const float* W_dec    = (const float*)d_in[6];
    const float* b_dec    = (const float*)d_in[7];
    const float* W_att    = (const float*)d_in[8];
    const float* b_att    = (const float*)d_in[9];
    const float* conv_w   = (const float*)d_in[10];
    const float* gvec     = (const float*)d_in[11];
    const float* W_o      = (const float*)d_in[12];
    const float* b_o      = (const float*)d_in[13];

    float* out_c    = (float*)d_out;           /* 32*1024 */
    float* out_attn = out_c + BATCH * KDIM;    /* 32*2000 */

    char* ws = (char*)d_ws;
    _Float16* Wet = (_Float16*)(ws + OFF_WENCT);
    _Float16* Wat = (_Float16*)(ws + OFF_WATTT);

    const size_t needMain = (size_t)M_ENCH + (size_t)ROWS * KDIM * 2;
    const bool f16p = ws_size >= needMain;

    if (f16p) {
        _Float16* convH = (_Float16*)(ws + OFF_CONV);
        float*    dterm = (float*)(ws + M_DTERM);
        float*    epart = (float*)(ws + M_EPART);
        float*    cpart = (float*)(ws + M_CPART);
        _Float16* encH  = (_Float16*)(ws + M_ENCH);

        k_prep<<<1153 + 8000, 256, 0, stream>>>(W_enc, W_att, dec_h, W_dec, b_enc, b_dec,
                                                b_att, att_prev, conv_w, enc,
                                                Wet, Wat, dterm, convH, encH, 1);
        k_gemm_e4<<<2000, 256, 0, stream>>>(encH, Wet, convH, Wat, dterm, gvec, epart);
        k_softmax<<<BATCH, 512, 0, stream>>>(epart, enc_len, out_attn, 4);
        k_cpart_h<<<dim3(40, BATCH), 256, 0, stream>>>(out_attn, encH, cpart);
        k_out<<<dim3(BATCH, 4), 256, 0, stream>>>(cpart, W_o, b_o, out_c, 40);
    } else {
        float* convF = (float*)(ws + OFF_CONV);
        float* dterm = (float*)(ws + F_DTERM);
        float* epart = (float*)(ws + F_EPART);
        float* cpart = (float*)(ws + F_CPART);

        k_prep<<<1153, 256, 0, stream>>>(W_enc, W_att, dec_h, W_dec, b_enc, b_dec,
                                         b_att, att_prev, conv_w, enc,
                                         Wet, Wat, dterm, convF, (_Float16*)nullptr, 0);
        k_gemm_f<<<2000, 256, 0, stream>>>(enc, Wet, convF, Wat, dterm, gvec, epart);
        k_softmax<<<BATCH, 512, 0, stream>>>(epart, enc_len, out_attn, 4);
        k_cpart_f<<<dim3(16, BATCH), 256, 0, stream>>>(out_attn, enc, cpart);
        k_out<<<dim3(BATCH, 4), 256, 0, stream>>>(cpart, W_o, b_o, out_c, 16);
    }
}

// Round 6
// 611.126 us; speedup vs baseline: 1.5626x; 1.0781x over previous
//
#include <hip/hip_runtime.h>
#include <stdint.h>
#include <stddef.h>

#define T_LEN   2000
#define BATCH   32
#define ROWS    64000      /* B*T */
#define KDIM    1024
#define ADIM    512
#define CCH     32
#define KW      101        /* 2*50+1 */

typedef _Float16 half8_t  __attribute__((ext_vector_type(8)));
typedef _Float16 half4_t  __attribute__((ext_vector_type(4)));
typedef float    float4_t __attribute__((ext_vector_type(4)));

__device__ __forceinline__ half8_t pack8(float4_t a, float4_t b) {
    half8_t r;
    r[0] = (_Float16)a.x; r[1] = (_Float16)a.y;
    r[2] = (_Float16)a.z; r[3] = (_Float16)a.w;
    r[4] = (_Float16)b.x; r[5] = (_Float16)b.y;
    r[6] = (_Float16)b.z; r[7] = (_Float16)b.w;
    return r;
}

__device__ __forceinline__ float tanh_fast(float x) {
    float ax = __builtin_fabsf(x);
    ax = fminf(ax, 15.f);
    float e = __expf(2.f * ax);
    float t = 1.f - 2.f * __builtin_amdgcn_rcpf(e + 1.f);
    return (x < 0.f) ? -t : t;
}

/* async global->LDS, 16B/lane; LDS dest = wave-uniform base + lane*16 */
__device__ __forceinline__ void glds16(const void* g, void* l) {
    __builtin_amdgcn_global_load_lds((const __attribute__((address_space(1))) uint32_t*)g,
                                     (__attribute__((address_space(3))) uint32_t*)l,
                                     16, 0, 0);
}

/* ---- ws layouts (bytes) ----
 * main (f16):  WENCT 0 | WATTT 1048576 | CONVH 1081344 (4MB f16) | DTERM 5177344
 *              | EPART 5242880 (4x64000 f32) | CPART 6266880 | ENCH 8364032 (131MB)
 * fallback:    same head but CONVF 1081344 is 8MB f32 -> DTERM 9273344,
 *              EPART 9338880, CPART 10362880, end 12460032                     */
#define OFF_WENCT 0
#define OFF_WATTT 1048576
#define OFF_CONV  1081344
#define M_DTERM   5177344
#define M_EPART   5242880
#define M_CPART   6266880
#define M_ENCH    8364032
#define F_DTERM   9273344
#define F_EPART   9338880
#define F_CPART   10362880

/* ---- fused prep: [0,512) We transpose, [512,640) dterm, [640,1152) conv,
 *      [1152] Wat, [1153, 1153+32000) enc->f16 conversion (main path only) ---- */
__global__ __launch_bounds__(256) void k_prep(const float* __restrict__ We,
                                              const float* __restrict__ Wa,
                                              const float* __restrict__ dec_h,
                                              const float* __restrict__ W_dec,
                                              const float* __restrict__ be,
                                              const float* __restrict__ bd,
                                              const float* __restrict__ ba,
                                              const float* __restrict__ att_prev,
                                              const float* __restrict__ conv_w,
                                              const float* __restrict__ enc,
                                              _Float16* __restrict__ Wet,
                                              _Float16* __restrict__ Wat,
                                              float* __restrict__ dterm,
                                              void* __restrict__ convO,
                                              _Float16* __restrict__ encH,
                                              int f16mode) {
    __shared__ float smem[3460];
    const int blk = blockIdx.x, tid = threadIdx.x;

    if (blk >= 1153) {
        /* enc fp32 -> f16, 2048 elems/block */
        const size_t idx = (size_t)(blk - 1153) * 2048 + tid * 8;
        const float4_t* s = (const float4_t*)(enc + idx);
        float4_t v0 = s[0], v1 = s[1];
        *(half8_t*)(encH + idx) = pack8(v0, v1);
        return;
    }
    if (blk < 512) {
        float (*tile)[33] = (float(*)[33])smem;
        const int k0 = (blk >> 4) * 32, n0 = (blk & 15) * 32;
        const int tx = tid & 31, ty = tid >> 5;
#pragma unroll
        for (int i = 0; i < 4; ++i)
            tile[ty + i * 8][tx] = We[(size_t)(k0 + ty + i * 8) * ADIM + n0 + tx];
        __syncthreads();
#pragma unroll
        for (int i = 0; i < 4; ++i)
            Wet[(size_t)(n0 + ty + i * 8) * KDIM + k0 + tx] = (_Float16)tile[tx][ty + i * 8];
    } else if (blk < 640) {
        float* dh = smem;
        float* part = smem + 1024;
        const int idx = blk - 512, b = idx >> 2, a0 = (idx & 3) * 128;
#pragma unroll
        for (int i = 0; i < 4; ++i) dh[tid + i * 256] = dec_h[b * KDIM + tid + i * 256];
        __syncthreads();
        const int a = a0 + (tid & 127), kh = (tid >> 7) * 512;
        float s = 0.f;
#pragma unroll 8
        for (int k = 0; k < 512; ++k) s += dh[kh + k] * W_dec[(size_t)(kh + k) * ADIM + a];
        part[tid] = s;
        __syncthreads();
        if (tid < 128) {
            const int aa = a0 + tid;
            dterm[b * ADIM + aa] = part[tid] + part[tid + 128] + be[aa] + bd[aa] + ba[aa];
        }
    } else if (blk < 1152) {
        float* ap = smem;
        float* w  = smem + 228;
        const int idx = blk - 640, b = idx >> 4, tt = idx & 15;
        const int t0 = tt * 128;
        for (int i = tid; i < 228; i += 256) {
            int t = t0 - 50 + i;
            ap[i] = (t >= 0 && t < T_LEN) ? att_prev[b * T_LEN + t] : 0.f;
        }
        for (int i = tid; i < CCH * KW; i += 256) w[i] = conv_w[i];
        __syncthreads();
        for (int idx2 = tid; idx2 < 128 * CCH; idx2 += 256) {
            int tl = idx2 >> 5, c = idx2 & 31;
            int t = t0 + tl;
            if (t < T_LEN) {
                float s = 0.f;
#pragma unroll
                for (int j = 0; j < KW; ++j) s += ap[tl + j] * w[c * KW + j];
                const size_t o = (size_t)(b * T_LEN + t) * CCH + c;
                if (f16mode) ((_Float16*)convO)[o] = (_Float16)s;
                else         ((float*)convO)[o] = s;
            }
        }
    } else {
#pragma unroll
        for (int rr = 0; rr < 2; ++rr) {
            const int n = tid * 2 + rr;
#pragma unroll
            for (int c = 0; c < CCH; ++c)
                Wat[n * CCH + c] = (_Float16)Wa[c * ADIM + n];
        }
    }
}

/* Fused GEMM+tanh+dot. 2000 blocks (XCD-swizzled so the 4 nc-siblings of an
 * m-tile share one XCD's L2), 256 thr = 4 waves, tile 128x128, wave 64x64.
 * Double-buffered all-glds staging, seg-major lane mapping (2-way-max LDS
 * reads by construction), one barrier per K-step.
 * F16A: A staged from pre-converted encH (8KB/step); else fp32 enc (16KB). */
template<bool F16A>
__global__ __launch_bounds__(256, F16A ? 4 : 3)
void k_gemm_e(const void* __restrict__ encv,
              const _Float16* __restrict__ Wet,
              const void* __restrict__ convv,
              const _Float16* __restrict__ Wat,
              const float* __restrict__ dterm,
              const float* __restrict__ gvec,
              float* __restrict__ epart) {
    constexpr int ABYTES = F16A ? 8192 : 16384;
    __shared__ __attribute__((aligned(16))) char     Ab[2][ABYTES];
    __shared__ __attribute__((aligned(16))) _Float16 Bh[2][128 * 32];

    const int tid  = threadIdx.x;
    const int blk  = blockIdx.x;
    int nc, mt;
    if (blk < 1984) { nc = (blk >> 3) & 3; mt = (blk >> 5) * 8 + (blk & 7); }
    else            { int r = blk - 1984; nc = r >> 2; mt = 496 + (r & 3); }
    const int m0 = mt * 128, n0 = nc * 128;

    const int wave = tid >> 6, lane = tid & 63;
    const int quad = lane >> 4, c16 = lane & 15;
    const int wm = (wave >> 1) * 64, wn = (wave & 1) * 64;

    /* staging lane roles (seg-major): A f16/B: lane = seg*16+row; A f32: seg*8+row */
    const int rlB = lane & 15, sgB = lane >> 4;
    const int rlA = F16A ? (lane & 15) : (lane & 7);
    const int sgA = F16A ? (lane >> 4) : (lane >> 3);
    constexpr int AISS = F16A ? 2 : 4;              /* A glds issues per wave */
    constexpr int ARPC = F16A ? 16 : 8;             /* A rows per 1KB chunk   */
    constexpr int AEPS = F16A ? 8 : 4;              /* A elems per 16B seg    */

    const _Float16* encH = (const _Float16*)encv;
    const float*    encF = (const float*)encv;
    const _Float16* cvH  = (const _Float16*)convv;
    const float*    cvF  = (const float*)convv;

    /* per-lane global element offsets (row*stride + seg) */
    const size_t aRow = (size_t)(m0 + wave * 32 + rlA);
    const size_t bRow = (size_t)(n0 + wave * 32 + rlB);

    /* epilogue data */
    float g[4], dt0[4], dt1[4];
    const int b0 = m0 / T_LEN, b1 = (m0 + 127) / T_LEN;
    const int lim = (b0 + 1) * T_LEN;
#pragma unroll
    for (int j = 0; j < 4; ++j) {
        const int col = n0 + wn + j * 16 + c16;
        g[j]   = gvec[col];
        dt0[j] = dterm[b0 * ADIM + col];
        dt1[j] = dterm[b1 * ADIM + col];
    }

    float4_t acc[4][4];
#pragma unroll
    for (int i = 0; i < 4; ++i)
#pragma unroll
        for (int j = 0; j < 4; ++j) acc[i][j] = (float4_t){0.f, 0.f, 0.f, 0.f};

    /* ---- staging helpers (k0 = element column offset within row) ---- */
#define STAGE_A(buf, base, stride, k0)                                              \
    _Pragma("unroll")                                                               \
    for (int i = 0; i < AISS; ++i)                                                  \
        glds16((base) + ((aRow + i * ARPC) * (stride)) + (k0) + sgA * AEPS,         \
               &Ab[buf][(wave * AISS + i) * 1024]);
#define STAGE_B(buf, base, stride, k0)                                              \
    _Pragma("unroll")                                                               \
    for (int i = 0; i < 2; ++i)                                                     \
        glds16((base) + ((bRow + i * 16) * (stride)) + (k0) + sgB * 8,              \
               (char*)&Bh[buf][0] + (wave * 2 + i) * 1024);

    /* prologue: stage K-step 0 into buf 0 */
    if (F16A) { STAGE_A(0, encH, KDIM, 0) } else { STAGE_A(0, encF, KDIM, 0) }
    STAGE_B(0, Wet, KDIM, 0)
    __syncthreads();

    for (int kk = 0; kk < 33; ++kk) {
        const int cur = kk & 1, nxt = cur ^ 1;
        if (kk < 31) {
            const int kn = (kk + 1) * 32;
            if (F16A) { STAGE_A(nxt, encH, KDIM, kn) } else { STAGE_A(nxt, encF, KDIM, kn) }
            STAGE_B(nxt, Wet, KDIM, kn)
        } else if (kk == 31) {   /* stage the conv K-step */
            if (F16A) { STAGE_A(nxt, cvH, CCH, 0) } else { STAGE_A(nxt, cvF, CCH, 0) }
            STAGE_B(nxt, Wat, CCH, 0)
        }
        half8_t af[4], bf[4];
        if (F16A) {
            const _Float16* Ah = (const _Float16*)Ab[cur];
#pragma unroll
            for (int i = 0; i < 4; ++i) {
                const int row = wm + i * 16 + c16;
                af[i] = *(const half8_t*)(Ah + (row >> 4) * 512 + (quad * 16 + c16) * 8);
            }
        } else {
            const float* Afp = (const float*)Ab[cur];
#pragma unroll
            for (int i = 0; i < 4; ++i) {
                const int row = wm + i * 16 + c16;
                const float* cb = Afp + (row >> 3) * 256 + (row & 7) * 4;
                float4_t u0 = *(const float4_t*)(cb + (2 * quad) * 32);
                float4_t u1 = *(const float4_t*)(cb + (2 * quad + 1) * 32);
                af[i] = pack8(u0, u1);
            }
        }
#pragma unroll
        for (int j = 0; j < 4; ++j) {
            const int row = wn + j * 16 + c16;
            bf[j] = *(const half8_t*)(&Bh[cur][0] + (row >> 4) * 512 + (quad * 16 + c16) * 8);
        }
#pragma unroll
        for (int i = 0; i < 4; ++i)
#pragma unroll
            for (int j = 0; j < 4; ++j)
                acc[i][j] = __builtin_amdgcn_mfma_f32_16x16x32_f16(af[i], bf[j], acc[i][j], 0, 0, 0);
        __syncthreads();
    }

    /* epilogue: + dterm, tanh, *g, 16-lane reduce, combine 2 n-waves */
    float* e_lds = (float*)&Bh[0][0];   /* [128][2] floats */
#pragma unroll
    for (int i = 0; i < 4; ++i) {
#pragma unroll
        for (int r = 0; r < 4; ++r) {
            const int rloc = wm + i * 16 + quad * 4 + r;
            const bool hi = (m0 + rloc) >= lim;
            float s = 0.f;
#pragma unroll
            for (int j = 0; j < 4; ++j)
                s += tanh_fast(acc[i][j][r] + (hi ? dt1[j] : dt0[j])) * g[j];
#pragma unroll
            for (int off = 1; off < 16; off <<= 1) s += __shfl_xor(s, off);
            if (c16 == 0) e_lds[rloc * 2 + (wave & 1)] = s;
        }
    }
    __syncthreads();
    if (tid < 128) {
        const float2 q = ((const float2*)e_lds)[tid];
        epart[nc * ROWS + m0 + tid] = q.x + q.y;
    }
#undef STAGE_A
#undef STAGE_B
}

/* softmax over T; logit = 2*sum_nc epart, masked -> -2e15 */
__global__ __launch_bounds__(512) void k_softmax(const float* __restrict__ epart,
                                                 const int* __restrict__ enc_len,
                                                 float* __restrict__ attn) {
    __shared__ float ex[T_LEN];
    __shared__ float red[8];
    const int b = blockIdx.x, tid = threadIdx.x;
    const int len = enc_len[b];
    float lmax = -3.4e38f;
    for (int t = tid; t < T_LEN; t += 512) {
        float e = epart[b * T_LEN + t] + epart[ROWS + b * T_LEN + t]
                + epart[2 * ROWS + b * T_LEN + t] + epart[3 * ROWS + b * T_LEN + t];
        float lg = (t < len) ? 2.f * e : -2e15f;
        ex[t] = lg;
        lmax = fmaxf(lmax, lg);
    }
    for (int off = 1; off < 64; off <<= 1) lmax = fmaxf(lmax, __shfl_xor(lmax, off));
    if ((tid & 63) == 0) red[tid >> 6] = lmax;
    __syncthreads();
    const float m = fmaxf(fmaxf(fmaxf(red[0], red[1]), fmaxf(red[2], red[3])),
                          fmaxf(fmaxf(red[4], red[5]), fmaxf(red[6], red[7])));
    float lsum = 0.f;
    for (int t = tid; t < T_LEN; t += 512) {
        float p = __expf(ex[t] - m);
        ex[t] = p;
        lsum += p;
    }
    for (int off = 1; off < 64; off <<= 1) lsum += __shfl_xor(lsum, off);
    __syncthreads();
    if ((tid & 63) == 0) red[tid >> 6] = lsum;
    __syncthreads();
    const float inv = 1.f / (red[0] + red[1] + red[2] + red[3] + red[4] + red[5] + red[6] + red[7]);
    for (int t = tid; t < T_LEN; t += 512) attn[b * T_LEN + t] = ex[t] * inv;
}

/* c partial from f16 enc copy */
__global__ __launch_bounds__(256) void k_cpart_h(const float* __restrict__ attn,
                                                 const _Float16* __restrict__ encH,
                                                 float* __restrict__ cpart) {
    const int b = blockIdx.y, tc = blockIdx.x, tid = threadIdx.x;
    const int t0 = tc * 125;
    float4_t s = (float4_t){0.f, 0.f, 0.f, 0.f};
    const half4_t* ep = (const half4_t*)(encH + (size_t)b * T_LEN * KDIM) + tid;
    const float* ap = attn + b * T_LEN + t0;
#pragma unroll 5
    for (int tt = 0; tt < 125; ++tt) {
        const float w = ap[tt];
        half4_t v = ep[(size_t)(t0 + tt) * 256];
        s.x += w * (float)v[0]; s.y += w * (float)v[1];
        s.z += w * (float)v[2]; s.w += w * (float)v[3];
    }
    *(float4_t*)&cpart[(size_t)(tc * BATCH + b) * KDIM + tid * 4] = s;
}

/* c partial from fp32 enc (fallback) */
__global__ __launch_bounds__(256) void k_cpart_f(const float* __restrict__ attn,
                                                 const float* __restrict__ enc,
                                                 float* __restrict__ cpart) {
    const int b = blockIdx.y, tc = blockIdx.x, tid = threadIdx.x;
    const int t0 = tc * 125;
    float4_t s = (float4_t){0.f, 0.f, 0.f, 0.f};
    const float4_t* ep = (const float4_t*)(enc + (size_t)b * T_LEN * KDIM) + tid;
    const float* ap = attn + b * T_LEN + t0;
#pragma unroll 5
    for (int tt = 0; tt < 125; ++tt) {
        const float w = ap[tt];
        float4_t v = ep[(size_t)(t0 + tt) * 256];
        s += v * w;
    }
    *(float4_t*)&cpart[(size_t)(tc * BATCH + b) * KDIM + tid * 4] = s;
}

/* out_c[b][o] = b_o[o] + sum_d (sum_p cpart[p][b][d]) * W_o[d][o] ; grid (32,4) x 256 */
__global__ __launch_bounds__(256) void k_out(const float* __restrict__ cpart,
                                             const float* __restrict__ W_o,
                                             const float* __restrict__ b_o,
                                             float* __restrict__ out_c) {
    __shared__ float cm[KDIM];
    const int b = blockIdx.x, tid = threadIdx.x;
    for (int d = tid; d < KDIM; d += 256) {
        float s = 0.f;
#pragma unroll
        for (int p = 0; p < 16; ++p) s += cpart[(size_t)(p * BATCH + b) * KDIM + d];
        cm[d] = s;
    }
    __syncthreads();
    const int o = blockIdx.y * 256 + tid;
    float s = b_o[o];
#pragma unroll 8
    for (int d = 0; d < KDIM; ++d) s += cm[d] * W_o[(size_t)d * KDIM + o];
    out_c[b * KDIM + o] = s;
}

extern "C" void kernel_launch(void* const* d_in, const int* in_sizes, int n_in,
                              void* d_out, int out_size, void* d_ws, size_t ws_size,
                              hipStream_t stream) {
    const float* enc      = (const float*)d_in[0];
    const int*   enc_len  = (const int*)d_in[1];
    const float* dec_h    = (const float*)d_in[2];
    const float* att_prev = (const float*)d_in[3];
    const float* W_enc    = (const float*)d_in[4];
    const float* b_enc    = (const float*)d_in[5];
    const float* W_dec    = (const float*)d_in[6];
    const float* b_dec    = (const float*)d_in[7];
    const float* W_att    = (const float*)d_in[8];
    const float* b_att    = (const float*)d_in[9];
    const float* conv_w   = (const float*)d_in[10];
    const float* gvec     = (const float*)d_in[11];
    const float* W_o      = (const float*)d_in[12];
    const float* b_o      = (const float*)d_in[13];

    float* out_c    = (float*)d_out;           /* 32*1024 */
    float* out_attn = out_c + BATCH * KDIM;    /* 32*2000 */

    char* ws = (char*)d_ws;
    _Float16* Wet = (_Float16*)(ws + OFF_WENCT);
    _Float16* Wat = (_Float16*)(ws + OFF_WATTT);

    const size_t needMain = (size_t)M_ENCH + (size_t)ROWS * KDIM * 2;
    const bool f16p = ws_size >= needMain;

    if (f16p) {
        _Float16* convH = (_Float16*)(ws + OFF_CONV);
        float*    dterm = (float*)(ws + M_DTERM);
        float*    epart = (float*)(ws + M_EPART);
        float*    cpart = (float*)(ws + M_CPART);
        _Float16* encH  = (_Float16*)(ws + M_ENCH);

        k_prep<<<1153 + 32000, 256, 0, stream>>>(W_enc, W_att, dec_h, W_dec, b_enc, b_dec,
                                                 b_att, att_prev, conv_w, enc,
                                                 Wet, Wat, dterm, convH, encH, 1);
        k_gemm_e<true><<<2000, 256, 0, stream>>>(encH, Wet, convH, Wat, dterm, gvec, epart);
        k_softmax<<<BATCH, 512, 0, stream>>>(epart, enc_len, out_attn);
        k_cpart_h<<<dim3(16, BATCH), 256, 0, stream>>>(out_attn, encH, cpart);
        k_out<<<dim3(BATCH, 4), 256, 0, stream>>>(cpart, W_o, b_o, out_c);
    } else {
        float* convF = (float*)(ws + OFF_CONV);
        float* dterm = (float*)(ws + F_DTERM);
        float* epart = (float*)(ws + F_EPART);
        float* cpart = (float*)(ws + F_CPART);

        k_prep<<<1153, 256, 0, stream>>>(W_enc, W_att, dec_h, W_dec, b_enc, b_dec,
                                         b_att, att_prev, conv_w, enc,
                                         Wet, Wat, dterm, convF, (_Float16*)nullptr, 0);
        k_gemm_e<false><<<2000, 256, 0, stream>>>(enc, Wet, convF, Wat, dterm, gvec, epart);
        k_softmax<<<BATCH, 512, 0, stream>>>(epart, enc_len, out_attn);
        k_cpart_f<<<dim3(16, BATCH), 256, 0, stream>>>(out_attn, enc, cpart);
        k_out<<<dim3(BATCH, 4), 256, 0, stream>>>(cpart, W_o, b_o, out_c);
    }
}

// Round 7
// 607.527 us; speedup vs baseline: 1.5719x; 1.0059x over previous
//
#include <hip/hip_runtime.h>
#include <stdint.h>
#include <stddef.h>

#define T_LEN   2000
#define BATCH   32
#define ROWS    64000      /* B*T */
#define KDIM    1024
#define ADIM    512
#define CCH     32
#define KW      101        /* 2*50+1 */

typedef _Float16 half8_t  __attribute__((ext_vector_type(8)));
typedef _Float16 half4_t  __attribute__((ext_vector_type(4)));
typedef float    float4_t __attribute__((ext_vector_type(4)));

__device__ __forceinline__ half8_t pack8(float4_t a, float4_t b) {
    half8_t r;
    r[0] = (_Float16)a.x; r[1] = (_Float16)a.y;
    r[2] = (_Float16)a.z; r[3] = (_Float16)a.w;
    r[4] = (_Float16)b.x; r[5] = (_Float16)b.y;
    r[6] = (_Float16)b.z; r[7] = (_Float16)b.w;
    return r;
}

__device__ __forceinline__ float tanh_fast(float x) {
    float ax = __builtin_fabsf(x);
    ax = fminf(ax, 15.f);
    float e = __expf(2.f * ax);
    float t = 1.f - 2.f * __builtin_amdgcn_rcpf(e + 1.f);
    return (x < 0.f) ? -t : t;
}

/* async global->LDS, 16B/lane; LDS dest = wave-uniform base + lane*16 */
__device__ __forceinline__ void glds16(const void* g, void* l) {
    __builtin_amdgcn_global_load_lds((const __attribute__((address_space(1))) uint32_t*)g,
                                     (__attribute__((address_space(3))) uint32_t*)l,
                                     16, 0, 0);
}

/* ---- ws layouts (bytes) ----
 * main (f16):  WENCT 0 | WATTT 1048576 | CONVH 1081344 (4MB f16) | DTERM 5177344
 *              | EPART 5242880 (4x64000 f32) | CPART 6266880 | ENCH 8364032 (131MB)
 * fallback:    same head but CONVF 1081344 is 8MB f32 -> DTERM 9273344,
 *              EPART 9338880, CPART 10362880, end 12460032                     */
#define OFF_WENCT 0
#define OFF_WATTT 1048576
#define OFF_CONV  1081344
#define M_DTERM   5177344
#define M_EPART   5242880
#define M_CPART   6266880
#define M_ENCH    8364032
#define F_DTERM   9273344
#define F_EPART   9338880
#define F_CPART   10362880

/* ---- fused prep: [0,512) We transpose, [512,640) dterm, [640,1152) conv,
 *      [1152] Wat, [1153, 1153+32000) enc->f16 conversion (main path only) ---- */
__global__ __launch_bounds__(256) void k_prep(const float* __restrict__ We,
                                              const float* __restrict__ Wa,
                                              const float* __restrict__ dec_h,
                                              const float* __restrict__ W_dec,
                                              const float* __restrict__ be,
                                              const float* __restrict__ bd,
                                              const float* __restrict__ ba,
                                              const float* __restrict__ att_prev,
                                              const float* __restrict__ conv_w,
                                              const float* __restrict__ enc,
                                              _Float16* __restrict__ Wet,
                                              _Float16* __restrict__ Wat,
                                              float* __restrict__ dterm,
                                              void* __restrict__ convO,
                                              _Float16* __restrict__ encH,
                                              int f16mode) {
    __shared__ float smem[3460];
    const int blk = blockIdx.x, tid = threadIdx.x;

    if (blk >= 1153) {
        /* enc fp32 -> f16, 2048 elems/block */
        const size_t idx = (size_t)(blk - 1153) * 2048 + tid * 8;
        const float4_t* s = (const float4_t*)(enc + idx);
        float4_t v0 = s[0], v1 = s[1];
        *(half8_t*)(encH + idx) = pack8(v0, v1);
        return;
    }
    if (blk < 512) {
        float (*tile)[33] = (float(*)[33])smem;
        const int k0 = (blk >> 4) * 32, n0 = (blk & 15) * 32;
        const int tx = tid & 31, ty = tid >> 5;
#pragma unroll
        for (int i = 0; i < 4; ++i)
            tile[ty + i * 8][tx] = We[(size_t)(k0 + ty + i * 8) * ADIM + n0 + tx];
        __syncthreads();
#pragma unroll
        for (int i = 0; i < 4; ++i)
            Wet[(size_t)(n0 + ty + i * 8) * KDIM + k0 + tx] = (_Float16)tile[tx][ty + i * 8];
    } else if (blk < 640) {
        float* dh = smem;
        float* part = smem + 1024;
        const int idx = blk - 512, b = idx >> 2, a0 = (idx & 3) * 128;
#pragma unroll
        for (int i = 0; i < 4; ++i) dh[tid + i * 256] = dec_h[b * KDIM + tid + i * 256];
        __syncthreads();
        const int a = a0 + (tid & 127), kh = (tid >> 7) * 512;
        float s = 0.f;
#pragma unroll 8
        for (int k = 0; k < 512; ++k) s += dh[kh + k] * W_dec[(size_t)(kh + k) * ADIM + a];
        part[tid] = s;
        __syncthreads();
        if (tid < 128) {
            const int aa = a0 + tid;
            dterm[b * ADIM + aa] = part[tid] + part[tid + 128] + be[aa] + bd[aa] + ba[aa];
        }
    } else if (blk < 1152) {
        float* ap = smem;
        float* w  = smem + 228;
        const int idx = blk - 640, b = idx >> 4, tt = idx & 15;
        const int t0 = tt * 128;
        for (int i = tid; i < 228; i += 256) {
            int t = t0 - 50 + i;
            ap[i] = (t >= 0 && t < T_LEN) ? att_prev[b * T_LEN + t] : 0.f;
        }
        for (int i = tid; i < CCH * KW; i += 256) w[i] = conv_w[i];
        __syncthreads();
        for (int idx2 = tid; idx2 < 128 * CCH; idx2 += 256) {
            int tl = idx2 >> 5, c = idx2 & 31;
            int t = t0 + tl;
            if (t < T_LEN) {
                float s = 0.f;
#pragma unroll
                for (int j = 0; j < KW; ++j) s += ap[tl + j] * w[c * KW + j];
                const size_t o = (size_t)(b * T_LEN + t) * CCH + c;
                if (f16mode) ((_Float16*)convO)[o] = (_Float16)s;
                else         ((float*)convO)[o] = s;
            }
        }
    } else {
#pragma unroll
        for (int rr = 0; rr < 2; ++rr) {
            const int n = tid * 2 + rr;
#pragma unroll
            for (int c = 0; c < CCH; ++c)
                Wat[n * CCH + c] = (_Float16)Wa[c * ADIM + n];
        }
    }
}

/* =====================================================================
 * Main-path fused GEMM+tanh+dot — round-0 compute, split-depth staging.
 * 2000 blocks (XCD-swizzled), 256 thr = 4 waves, tile 128x128, wave
 * 64x64, BK=32.
 * A (encH, HBM-streamed, ~900cy): 3 buffers, staged 2 steps ahead.
 * B (Wet, L2-resident, ~200cy):   2 buffers, staged 1 step ahead.
 * LDS = 3*8KB + 2*8KB = 40KB -> 4 blocks/CU (exact 160KB fit), 16
 * waves/CU. Per step: vmcnt(2) (A(k)+B(k) landed, A(k+1) flying) ->
 * s_barrier -> sched_barrier -> issue B(k+1), A(k+2) -> compute.
 * WAR: every staged buffer was last read at step k-1, behind the barrier.
 * ===================================================================== */
__global__ __launch_bounds__(256, 4)
void k_gemm_p(const _Float16* __restrict__ encH,
              const _Float16* __restrict__ Wet,
              const _Float16* __restrict__ cvH,
              const _Float16* __restrict__ Wat,
              const float* __restrict__ dterm,
              const float* __restrict__ gvec,
              float* __restrict__ epart) {
    __shared__ __attribute__((aligned(16))) char Ab[3][8192];
    __shared__ __attribute__((aligned(16))) char Bh[2][8192];

    const int tid  = threadIdx.x;
    const int blk  = blockIdx.x;
    int nc, mt;
    if (blk < 1984) { nc = (blk >> 3) & 3; mt = (blk >> 5) * 8 + (blk & 7); }
    else            { int r = blk - 1984; nc = r >> 2; mt = 496 + (r & 3); }
    const int m0 = mt * 128, n0 = nc * 128;

    const int wave = tid >> 6, lane = tid & 63;
    const int quad = lane >> 4, c16 = lane & 15;
    const int wm = (wave >> 1) * 64, wn = (wave & 1) * 64;
    const int rl = lane & 15, sg = lane >> 4;   /* seg-major 16B staging lanes */

    const size_t aRow = (size_t)(m0 + wave * 32 + rl);
    const size_t bRow = (size_t)(n0 + wave * 32 + rl);

    /* epilogue data */
    float g[4], dt0[4], dt1[4];
    const int b0 = m0 / T_LEN, b1 = (m0 + 127) / T_LEN;
    const int lim = (b0 + 1) * T_LEN;
#pragma unroll
    for (int j = 0; j < 4; ++j) {
        const int col = n0 + wn + j * 16 + c16;
        g[j]   = gvec[col];
        dt0[j] = dterm[b0 * ADIM + col];
        dt1[j] = dterm[b1 * ADIM + col];
    }

    float4_t acc[4][4];
#pragma unroll
    for (int i = 0; i < 4; ++i)
#pragma unroll
        for (int j = 0; j < 4; ++j) acc[i][j] = (float4_t){0.f, 0.f, 0.f, 0.f};

    /* stage A-step s into Ab[s%3]; stage B-step s into Bh[s&1]; s==32 = conv */
#define STG_A(s)                                                                     \
    {                                                                                \
        const int bf = (s) - ((s) / 3) * 3;                                          \
        if ((s) < 32) {                                                              \
            const int kn = (s) * 32;                                                 \
            glds16(encH + (aRow +  0) * KDIM + kn + sg * 8, &Ab[bf][(wave*2+0)*1024]); \
            glds16(encH + (aRow + 16) * KDIM + kn + sg * 8, &Ab[bf][(wave*2+1)*1024]); \
        } else {                                                                     \
            glds16(cvH + (aRow +  0) * CCH + sg * 8, &Ab[bf][(wave*2+0)*1024]);      \
            glds16(cvH + (aRow + 16) * CCH + sg * 8, &Ab[bf][(wave*2+1)*1024]);      \
        }                                                                            \
    }
#define STG_B(s)                                                                     \
    {                                                                                \
        const int bf = (s) & 1;                                                      \
        if ((s) < 32) {                                                              \
            const int kn = (s) * 32;                                                 \
            glds16(Wet + (bRow +  0) * KDIM + kn + sg * 8, &Bh[bf][(wave*2+0)*1024]); \
            glds16(Wet + (bRow + 16) * KDIM + kn + sg * 8, &Bh[bf][(wave*2+1)*1024]); \
        } else {                                                                     \
            glds16(Wat + (bRow +  0) * CCH + sg * 8, &Bh[bf][(wave*2+0)*1024]);      \
            glds16(Wat + (bRow + 16) * CCH + sg * 8, &Bh[bf][(wave*2+1)*1024]);      \
        }                                                                            \
    }

    /* prologue: B(0), A(0), A(1) -> per-wave queue [B0,B0,A0,A0,A1,A1] */
    STG_B(0)
    STG_A(0)
    STG_A(1)

    for (int kk = 0; kk < 33; ++kk) {
        /* retire A(kk) (issued 2 steps ago) + B(kk) (1 step ago); A(kk+1) flies */
        if (kk < 32) asm volatile("s_waitcnt vmcnt(2)" ::: "memory");
        else         asm volatile("s_waitcnt vmcnt(0)" ::: "memory");
        __builtin_amdgcn_s_barrier();
        __builtin_amdgcn_sched_barrier(0);

        if (kk + 1 <= 32) STG_B(kk + 1)
        if (kk + 2 <= 32) STG_A(kk + 2)

        const int cur3 = kk - (kk / 3) * 3;
        const int cur2 = kk & 1;
        const _Float16* Ah = (const _Float16*)Ab[cur3];
        const _Float16* Bp = (const _Float16*)Bh[cur2];
        half8_t af[4], bf4[4];
#pragma unroll
        for (int i = 0; i < 4; ++i) {
            const int row = wm + i * 16 + c16;
            af[i] = *(const half8_t*)(Ah + (row >> 4) * 512 + (quad * 16 + c16) * 8);
        }
#pragma unroll
        for (int j = 0; j < 4; ++j) {
            const int row = wn + j * 16 + c16;
            bf4[j] = *(const half8_t*)(Bp + (row >> 4) * 512 + (quad * 16 + c16) * 8);
        }
#pragma unroll
        for (int i = 0; i < 4; ++i)
#pragma unroll
            for (int j = 0; j < 4; ++j)
                acc[i][j] = __builtin_amdgcn_mfma_f32_16x16x32_f16(af[i], bf4[j], acc[i][j], 0, 0, 0);
    }
#undef STG_A
#undef STG_B
    __syncthreads();   /* all waves done reading LDS before epilogue reuse */

    /* epilogue: + dterm, tanh, *g, 16-lane reduce, combine 2 n-waves */
    float* e_lds = (float*)&Bh[0][0];   /* [128][2] floats */
#pragma unroll
    for (int i = 0; i < 4; ++i) {
#pragma unroll
        for (int r = 0; r < 4; ++r) {
            const int rloc = wm + i * 16 + quad * 4 + r;
            const bool hi = (m0 + rloc) >= lim;
            float s = 0.f;
#pragma unroll
            for (int j = 0; j < 4; ++j)
                s += tanh_fast(acc[i][j][r] + (hi ? dt1[j] : dt0[j])) * g[j];
#pragma unroll
            for (int off = 1; off < 16; off <<= 1) s += __shfl_xor(s, off);
            if (c16 == 0) e_lds[rloc * 2 + (wave & 1)] = s;
        }
    }
    __syncthreads();
    if (tid < 128) {
        const float2 q = ((const float2*)e_lds)[tid];
        epart[nc * ROWS + m0 + tid] = q.x + q.y;
    }
}

/* fallback-path GEMM (fp32 A), original 2-buffer structure */
template<bool F16A>
__global__ __launch_bounds__(256, F16A ? 4 : 3)
void k_gemm_e(const void* __restrict__ encv,
              const _Float16* __restrict__ Wet,
              const void* __restrict__ convv,
              const _Float16* __restrict__ Wat,
              const float* __restrict__ dterm,
              const float* __restrict__ gvec,
              float* __restrict__ epart) {
    constexpr int ABYTES = F16A ? 8192 : 16384;
    __shared__ __attribute__((aligned(16))) char     Ab[2][ABYTES];
    __shared__ __attribute__((aligned(16))) _Float16 Bh[2][128 * 32];

    const int tid  = threadIdx.x;
    const int blk  = blockIdx.x;
    int nc, mt;
    if (blk < 1984) { nc = (blk >> 3) & 3; mt = (blk >> 5) * 8 + (blk & 7); }
    else            { int r = blk - 1984; nc = r >> 2; mt = 496 + (r & 3); }
    const int m0 = mt * 128, n0 = nc * 128;

    const int wave = tid >> 6, lane = tid & 63;
    const int quad = lane >> 4, c16 = lane & 15;
    const int wm = (wave >> 1) * 64, wn = (wave & 1) * 64;

    const int rlB = lane & 15, sgB = lane >> 4;
    const int rlA = F16A ? (lane & 15) : (lane & 7);
    const int sgA = F16A ? (lane >> 4) : (lane >> 3);
    constexpr int AISS = F16A ? 2 : 4;
    constexpr int ARPC = F16A ? 16 : 8;
    constexpr int AEPS = F16A ? 8 : 4;

    const _Float16* encH = (const _Float16*)encv;
    const float*    encF = (const float*)encv;
    const _Float16* cvH  = (const _Float16*)convv;
    const float*    cvF  = (const float*)convv;

    const size_t aRow = (size_t)(m0 + wave * 32 + rlA);
    const size_t bRow = (size_t)(n0 + wave * 32 + rlB);

    float g[4], dt0[4], dt1[4];
    const int b0 = m0 / T_LEN, b1 = (m0 + 127) / T_LEN;
    const int lim = (b0 + 1) * T_LEN;
#pragma unroll
    for (int j = 0; j < 4; ++j) {
        const int col = n0 + wn + j * 16 + c16;
        g[j]   = gvec[col];
        dt0[j] = dterm[b0 * ADIM + col];
        dt1[j] = dterm[b1 * ADIM + col];
    }

    float4_t acc[4][4];
#pragma unroll
    for (int i = 0; i < 4; ++i)
#pragma unroll
        for (int j = 0; j < 4; ++j) acc[i][j] = (float4_t){0.f, 0.f, 0.f, 0.f};

#define STAGE_A(buf, base, stride, k0)                                              \
    _Pragma("unroll")                                                               \
    for (int i = 0; i < AISS; ++i)                                                  \
        glds16((base) + ((aRow + i * ARPC) * (stride)) + (k0) + sgA * AEPS,         \
               &Ab[buf][(wave * AISS + i) * 1024]);
#define STAGE_B(buf, base, stride, k0)                                              \
    _Pragma("unroll")                                                               \
    for (int i = 0; i < 2; ++i)                                                     \
        glds16((base) + ((bRow + i * 16) * (stride)) + (k0) + sgB * 8,              \
               (char*)&Bh[buf][0] + (wave * 2 + i) * 1024);

    if (F16A) { STAGE_A(0, encH, KDIM, 0) } else { STAGE_A(0, encF, KDIM, 0) }
    STAGE_B(0, Wet, KDIM, 0)
    __syncthreads();

    for (int kk = 0; kk < 33; ++kk) {
        const int cur = kk & 1, nxt = cur ^ 1;
        if (kk < 31) {
            const int kn = (kk + 1) * 32;
            if (F16A) { STAGE_A(nxt, encH, KDIM, kn) } else { STAGE_A(nxt, encF, KDIM, kn) }
            STAGE_B(nxt, Wet, KDIM, kn)
        } else if (kk == 31) {
            if (F16A) { STAGE_A(nxt, cvH, CCH, 0) } else { STAGE_A(nxt, cvF, CCH, 0) }
            STAGE_B(nxt, Wat, CCH, 0)
        }
        half8_t af[4], bf[4];
        if (F16A) {
            const _Float16* Ah = (const _Float16*)Ab[cur];
#pragma unroll
            for (int i = 0; i < 4; ++i) {
                const int row = wm + i * 16 + c16;
                af[i] = *(const half8_t*)(Ah + (row >> 4) * 512 + (quad * 16 + c16) * 8);
            }
        } else {
            const float* Afp = (const float*)Ab[cur];
#pragma unroll
            for (int i = 0; i < 4; ++i) {
                const int row = wm + i * 16 + c16;
                const float* cb = Afp + (row >> 3) * 256 + (row & 7) * 4;
                float4_t u0 = *(const float4_t*)(cb + (2 * quad) * 32);
                float4_t u1 = *(const float4_t*)(cb + (2 * quad + 1) * 32);
                af[i] = pack8(u0, u1);
            }
        }
#pragma unroll
        for (int j = 0; j < 4; ++j) {
            const int row = wn + j * 16 + c16;
            bf[j] = *(const half8_t*)(&Bh[cur][0] + (row >> 4) * 512 + (quad * 16 + c16) * 8);
        }
#pragma unroll
        for (int i = 0; i < 4; ++i)
#pragma unroll
            for (int j = 0; j < 4; ++j)
                acc[i][j] = __builtin_amdgcn_mfma_f32_16x16x32_f16(af[i], bf[j], acc[i][j], 0, 0, 0);
        __syncthreads();
    }

    float* e_lds = (float*)&Bh[0][0];
#pragma unroll
    for (int i = 0; i < 4; ++i) {
#pragma unroll
        for (int r = 0; r < 4; ++r) {
            const int rloc = wm + i * 16 + quad * 4 + r;
            const bool hi = (m0 + rloc) >= lim;
            float s = 0.f;
#pragma unroll
            for (int j = 0; j < 4; ++j)
                s += tanh_fast(acc[i][j][r] + (hi ? dt1[j] : dt0[j])) * g[j];
#pragma unroll
            for (int off = 1; off < 16; off <<= 1) s += __shfl_xor(s, off);
            if (c16 == 0) e_lds[rloc * 2 + (wave & 1)] = s;
        }
    }
    __syncthreads();
    if (tid < 128) {
        const float2 q = ((const float2*)e_lds)[tid];
        epart[nc * ROWS + m0 + tid] = q.x + q.y;
    }
#undef STAGE_A
#undef STAGE_B
}

/* softmax over T; logit = 2*sum_nc epart, masked -> -2e15 */
__global__ __launch_bounds__(512) void k_softmax(const float* __restrict__ epart,
                                                 const int* __restrict__ enc_len,
                                                 float* __restrict__ attn) {
    __shared__ float ex[T_LEN];
    __shared__ float red[8];
    const int b = blockIdx.x, tid = threadIdx.x;
    const int len = enc_len[b];
    float lmax = -3.4e38f;
    for (int t = tid; t < T_LEN; t += 512) {
        float e = epart[b * T_LEN + t] + epart[ROWS + b * T_LEN + t]
                + epart[2 * ROWS + b * T_LEN + t] + epart[3 * ROWS + b * T_LEN + t];
        float lg = (t < len) ? 2.f * e : -2e15f;
        ex[t] = lg;
        lmax = fmaxf(lmax, lg);
    }
    for (int off = 1; off < 64; off <<= 1) lmax = fmaxf(lmax, __shfl_xor(lmax, off));
    if ((tid & 63) == 0) red[tid >> 6] = lmax;
    __syncthreads();
    const float m = fmaxf(fmaxf(fmaxf(red[0], red[1]), fmaxf(red[2], red[3])),
                          fmaxf(fmaxf(red[4], red[5]), fmaxf(red[6], red[7])));
    float lsum = 0.f;
    for (int t = tid; t < T_LEN; t += 512) {
        float p = __expf(ex[t] - m);
        ex[t] = p;
        lsum += p;
    }
    for (int off = 1; off < 64; off <<= 1) lsum += __shfl_xor(lsum, off);
    __syncthreads();
    if ((tid & 63) == 0) red[tid >> 6] = lsum;
    __syncthreads();
    const float inv = 1.f / (red[0] + red[1] + red[2] + red[3] + red[4] + red[5] + red[6] + red[7]);
    for (int t = tid; t < T_LEN; t += 512) attn[b * T_LEN + t] = ex[t] * inv;
}

/* c partial from f16 enc copy */
__global__ __launch_bounds__(256) void k_cpart_h(const float* __restrict__ attn,
                                                 const _Float16* __restrict__ encH,
                                                 float* __restrict__ cpart) {
    const int b = blockIdx.y, tc = blockIdx.x, tid = threadIdx.x;
    const int t0 = tc * 125;
    float4_t s = (float4_t){0.f, 0.f, 0.f, 0.f};
    const half4_t* ep = (const half4_t*)(encH + (size_t)b * T_LEN * KDIM) + tid;
    const float* ap = attn + b * T_LEN + t0;
#pragma unroll 5
    for (int tt = 0; tt < 125; ++tt) {
        const float w = ap[tt];
        half4_t v = ep[(size_t)(t0 + tt) * 256];
        s.x += w * (float)v[0]; s.y += w * (float)v[1];
        s.z += w * (float)v[2]; s.w += w * (float)v[3];
    }
    *(float4_t*)&cpart[(size_t)(tc * BATCH + b) * KDIM + tid * 4] = s;
}

/* c partial from fp32 enc (fallback) */
__global__ __launch_bounds__(256) void k_cpart_f(const float* __restrict__ attn,
                                                 const float* __restrict__ enc,
                                                 float* __restrict__ cpart) {
    const int b = blockIdx.y, tc = blockIdx.x, tid = threadIdx.x;
    const int t0 = tc * 125;
    float4_t s = (float4_t){0.f, 0.f, 0.f, 0.f};
    const float4_t* ep = (const float4_t*)(enc + (size_t)b * T_LEN * KDIM) + tid;
    const float* ap = attn + b * T_LEN + t0;
#pragma unroll 5
    for (int tt = 0; tt < 125; ++tt) {
        const float w = ap[tt];
        float4_t v = ep[(size_t)(t0 + tt) * 256];
        s += v * w;
    }
    *(float4_t*)&cpart[(size_t)(tc * BATCH + b) * KDIM + tid * 4] = s;
}

/* out_c[b][o] = b_o[o] + sum_d (sum_p cpart[p][b][d]) * W_o[d][o] ; grid (32,4) x 256 */
__global__ __launch_bounds__(256) void k_out(const float* __restrict__ cpart,
                                             const float* __restrict__ W_o,
                                             const float* __restrict__ b_o,
                                             float* __restrict__ out_c) {
    __shared__ float cm[KDIM];
    const int b = blockIdx.x, tid = threadIdx.x;
    for (int d = tid; d < KDIM; d += 256) {
        float s = 0.f;
#pragma unroll
        for (int p = 0; p < 16; ++p) s += cpart[(size_t)(p * BATCH + b) * KDIM + d];
        cm[d] = s;
    }
    __syncthreads();
    const int o = blockIdx.y * 256 + tid;
    float s = b_o[o];
#pragma unroll 8
    for (int d = 0; d < KDIM; ++d) s += cm[d] * W_o[(size_t)d * KDIM + o];
    out_c[b * KDIM + o] = s;
}

extern "C" void kernel_launch(void* const* d_in, const int* in_sizes, int n_in,
                              void* d_out, int out_size, void* d_ws, size_t ws_size,
                              hipStream_t stream) {
    const float* enc      = (const float*)d_in[0];
    const int*   enc_len  = (const int*)d_in[1];
    const float* dec_h    = (const float*)d_in[2];
    const float* att_prev = (const float*)d_in[3];
    const float* W_enc    = (const float*)d_in[4];
    const float* b_enc    = (const float*)d_in[5];
    const float* W_dec    = (const float*)d_in[6];
    const float* b_dec    = (const float*)d_in[7];
    const float* W_att    = (const float*)d_in[8];
    const float* b_att    = (const float*)d_in[9];
    const float* conv_w   = (const float*)d_in[10];
    const float* gvec     = (const float*)d_in[11];
    const float* W_o      = (const float*)d_in[12];
    const float* b_o      = (const float*)d_in[13];

    float* out_c    = (float*)d_out;           /* 32*1024 */
    float* out_attn = out_c + BATCH * KDIM;    /* 32*2000 */

    char* ws = (char*)d_ws;
    _Float16* Wet = (_Float16*)(ws + OFF_WENCT);
    _Float16* Wat = (_Float16*)(ws + OFF_WATTT);

    const size_t needMain = (size_t)M_ENCH + (size_t)ROWS * KDIM * 2;
    const bool f16p = ws_size >= needMain;

    if (f16p) {
        _Float16* convH = (_Float16*)(ws + OFF_CONV);
        float*    dterm = (float*)(ws + M_DTERM);
        float*    epart = (float*)(ws + M_EPART);
        float*    cpart = (float*)(ws + M_CPART);
        _Float16* encH  = (_Float16*)(ws + M_ENCH);

        k_prep<<<1153 + 32000, 256, 0, stream>>>(W_enc, W_att, dec_h, W_dec, b_enc, b_dec,
                                                 b_att, att_prev, conv_w, enc,
                                                 Wet, Wat, dterm, convH, encH, 1);
        k_gemm_p<<<2000, 256, 0, stream>>>(encH, Wet, convH, Wat, dterm, gvec, epart);
        k_softmax<<<BATCH, 512, 0, stream>>>(epart, enc_len, out_attn);
        k_cpart_h<<<dim3(16, BATCH), 256, 0, stream>>>(out_attn, encH, cpart);
        k_out<<<dim3(BATCH, 4), 256, 0, stream>>>(cpart, W_o, b_o, out_c);
    } else {
        float* convF = (float*)(ws + OFF_CONV);
        float* dterm = (float*)(ws + F_DTERM);
        float* epart = (float*)(ws + F_EPART);
        float* cpart = (float*)(ws + F_CPART);

        k_prep<<<1153, 256, 0, stream>>>(W_enc, W_att, dec_h, W_dec, b_enc, b_dec,
                                         b_att, att_prev, conv_w, enc,
                                         Wet, Wat, dterm, convF, (_Float16*)nullptr, 0);
        k_gemm_e<false><<<2000, 256, 0, stream>>>(enc, Wet, convF, Wat, dterm, gvec, epart);
        k_softmax<<<BATCH, 512, 0, stream>>>(epart, enc_len, out_attn);
        k_cpart_f<<<dim3(16, BATCH), 256, 0, stream>>>(out_attn, enc, cpart);
        k_out<<<dim3(BATCH, 4), 256, 0, stream>>>(cpart, W_o, b_o, out_c);
    }
}

// Round 8
// 561.688 us; speedup vs baseline: 1.7001x; 1.0816x over previous
//
#include <hip/hip_runtime.h>
#include <stdint.h>
#include <stddef.h>

#define T_LEN   2000
#define BATCH   32
#define ROWS    64000      /* B*T */
#define KDIM    1024
#define ADIM    512
#define CCH     32
#define KW      101        /* 2*50+1 */

typedef _Float16 half8_t  __attribute__((ext_vector_type(8)));
typedef _Float16 half4_t  __attribute__((ext_vector_type(4)));
typedef float    float4_t __attribute__((ext_vector_type(4)));

__device__ __forceinline__ half8_t pack8(float4_t a, float4_t b) {
    half8_t r;
    r[0] = (_Float16)a.x; r[1] = (_Float16)a.y;
    r[2] = (_Float16)a.z; r[3] = (_Float16)a.w;
    r[4] = (_Float16)b.x; r[5] = (_Float16)b.y;
    r[6] = (_Float16)b.z; r[7] = (_Float16)b.w;
    return r;
}

__device__ __forceinline__ float tanh_fast(float x) {
    float ax = __builtin_fabsf(x);
    ax = fminf(ax, 15.f);
    float e = __expf(2.f * ax);
    float t = 1.f - 2.f * __builtin_amdgcn_rcpf(e + 1.f);
    return (x < 0.f) ? -t : t;
}

/* async global->LDS, 16B/lane; LDS dest = wave-uniform base + lane*16 */
__device__ __forceinline__ void glds16(const void* g, void* l) {
    __builtin_amdgcn_global_load_lds((const __attribute__((address_space(1))) uint32_t*)g,
                                     (__attribute__((address_space(3))) uint32_t*)l,
                                     16, 0, 0);
}

/* ---- ws layouts (bytes) ---- */
#define OFF_WENCT 0
#define OFF_WATTT 1048576
#define OFF_CONV  1081344
#define M_DTERM   5177344
#define M_EPART   5242880
#define M_CPART   6266880
#define M_ENCH    8364032
#define F_DTERM   9273344
#define F_EPART   9338880
#define F_CPART   10362880

/* ---- fused prep: [0,512) We transpose, [512,640) dterm, [640,1152) conv,
 *      [1152] Wat, [1153, 1153+32000) enc->f16 conversion (main path only) ---- */
__global__ __launch_bounds__(256) void k_prep(const float* __restrict__ We,
                                              const float* __restrict__ Wa,
                                              const float* __restrict__ dec_h,
                                              const float* __restrict__ W_dec,
                                              const float* __restrict__ be,
                                              const float* __restrict__ bd,
                                              const float* __restrict__ ba,
                                              const float* __restrict__ att_prev,
                                              const float* __restrict__ conv_w,
                                              const float* __restrict__ enc,
                                              _Float16* __restrict__ Wet,
                                              _Float16* __restrict__ Wat,
                                              float* __restrict__ dterm,
                                              void* __restrict__ convO,
                                              _Float16* __restrict__ encH,
                                              int f16mode) {
    __shared__ float smem[3460];
    const int blk = blockIdx.x, tid = threadIdx.x;

    if (blk >= 1153) {
        /* enc fp32 -> f16, 2048 elems/block */
        const size_t idx = (size_t)(blk - 1153) * 2048 + tid * 8;
        const float4_t* s = (const float4_t*)(enc + idx);
        float4_t v0 = s[0], v1 = s[1];
        *(half8_t*)(encH + idx) = pack8(v0, v1);
        return;
    }
    if (blk < 512) {
        float (*tile)[33] = (float(*)[33])smem;
        const int k0 = (blk >> 4) * 32, n0 = (blk & 15) * 32;
        const int tx = tid & 31, ty = tid >> 5;
#pragma unroll
        for (int i = 0; i < 4; ++i)
            tile[ty + i * 8][tx] = We[(size_t)(k0 + ty + i * 8) * ADIM + n0 + tx];
        __syncthreads();
#pragma unroll
        for (int i = 0; i < 4; ++i)
            Wet[(size_t)(n0 + ty + i * 8) * KDIM + k0 + tx] = (_Float16)tile[tx][ty + i * 8];
    } else if (blk < 640) {
        float* dh = smem;
        float* part = smem + 1024;
        const int idx = blk - 512, b = idx >> 2, a0 = (idx & 3) * 128;
#pragma unroll
        for (int i = 0; i < 4; ++i) dh[tid + i * 256] = dec_h[b * KDIM + tid + i * 256];
        __syncthreads();
        const int a = a0 + (tid & 127), kh = (tid >> 7) * 512;
        float s = 0.f;
#pragma unroll 8
        for (int k = 0; k < 512; ++k) s += dh[kh + k] * W_dec[(size_t)(kh + k) * ADIM + a];
        part[tid] = s;
        __syncthreads();
        if (tid < 128) {
            const int aa = a0 + tid;
            dterm[b * ADIM + aa] = part[tid] + part[tid + 128] + be[aa] + bd[aa] + ba[aa];
        }
    } else if (blk < 1152) {
        float* ap = smem;
        float* w  = smem + 228;
        const int idx = blk - 640, b = idx >> 4, tt = idx & 15;
        const int t0 = tt * 128;
        for (int i = tid; i < 228; i += 256) {
            int t = t0 - 50 + i;
            ap[i] = (t >= 0 && t < T_LEN) ? att_prev[b * T_LEN + t] : 0.f;
        }
        for (int i = tid; i < CCH * KW; i += 256) w[i] = conv_w[i];
        __syncthreads();
        for (int idx2 = tid; idx2 < 128 * CCH; idx2 += 256) {
            int tl = idx2 >> 5, c = idx2 & 31;
            int t = t0 + tl;
            if (t < T_LEN) {
                float s = 0.f;
#pragma unroll
                for (int j = 0; j < KW; ++j) s += ap[tl + j] * w[c * KW + j];
                const size_t o = (size_t)(b * T_LEN + t) * CCH + c;
                if (f16mode) ((_Float16*)convO)[o] = (_Float16)s;
                else         ((float*)convO)[o] = s;
            }
        }
    } else {
#pragma unroll
        for (int rr = 0; rr < 2; ++rr) {
            const int n = tid * 2 + rr;
#pragma unroll
            for (int c = 0; c < CCH; ++c)
                Wat[n * CCH + c] = (_Float16)Wa[c * ADIM + n];
        }
    }
}

/* =====================================================================
 * Main-path fused GEMM+tanh+dot — round-0 compute, split-depth staging.
 * (round-7 best: A 3-buf depth-2, B 2-buf depth-1, 40KB LDS, 4 blk/CU)
 * ===================================================================== */
__global__ __launch_bounds__(256, 4)
void k_gemm_p(const _Float16* __restrict__ encH,
              const _Float16* __restrict__ Wet,
              const _Float16* __restrict__ cvH,
              const _Float16* __restrict__ Wat,
              const float* __restrict__ dterm,
              const float* __restrict__ gvec,
              float* __restrict__ epart) {
    __shared__ __attribute__((aligned(16))) char Ab[3][8192];
    __shared__ __attribute__((aligned(16))) char Bh[2][8192];

    const int tid  = threadIdx.x;
    const int blk  = blockIdx.x;
    int nc, mt;
    if (blk < 1984) { nc = (blk >> 3) & 3; mt = (blk >> 5) * 8 + (blk & 7); }
    else            { int r = blk - 1984; nc = r >> 2; mt = 496 + (r & 3); }
    const int m0 = mt * 128, n0 = nc * 128;

    const int wave = tid >> 6, lane = tid & 63;
    const int quad = lane >> 4, c16 = lane & 15;
    const int wm = (wave >> 1) * 64, wn = (wave & 1) * 64;
    const int rl = lane & 15, sg = lane >> 4;   /* seg-major 16B staging lanes */

    const size_t aRow = (size_t)(m0 + wave * 32 + rl);
    const size_t bRow = (size_t)(n0 + wave * 32 + rl);

    /* epilogue data */
    float g[4], dt0[4], dt1[4];
    const int b0 = m0 / T_LEN, b1 = (m0 + 127) / T_LEN;
    const int lim = (b0 + 1) * T_LEN;
#pragma unroll
    for (int j = 0; j < 4; ++j) {
        const int col = n0 + wn + j * 16 + c16;
        g[j]   = gvec[col];
        dt0[j] = dterm[b0 * ADIM + col];
        dt1[j] = dterm[b1 * ADIM + col];
    }

    float4_t acc[4][4];
#pragma unroll
    for (int i = 0; i < 4; ++i)
#pragma unroll
        for (int j = 0; j < 4; ++j) acc[i][j] = (float4_t){0.f, 0.f, 0.f, 0.f};

    /* stage A-step s into Ab[s%3]; stage B-step s into Bh[s&1]; s==32 = conv */
#define STG_A(s)                                                                     \
    {                                                                                \
        const int bf = (s) - ((s) / 3) * 3;                                          \
        if ((s) < 32) {                                                              \
            const int kn = (s) * 32;                                                 \
            glds16(encH + (aRow +  0) * KDIM + kn + sg * 8, &Ab[bf][(wave*2+0)*1024]); \
            glds16(encH + (aRow + 16) * KDIM + kn + sg * 8, &Ab[bf][(wave*2+1)*1024]); \
        } else {                                                                     \
            glds16(cvH + (aRow +  0) * CCH + sg * 8, &Ab[bf][(wave*2+0)*1024]);      \
            glds16(cvH + (aRow + 16) * CCH + sg * 8, &Ab[bf][(wave*2+1)*1024]);      \
        }                                                                            \
    }
#define STG_B(s)                                                                     \
    {                                                                                \
        const int bf = (s) & 1;                                                      \
        if ((s) < 32) {                                                              \
            const int kn = (s) * 32;                                                 \
            glds16(Wet + (bRow +  0) * KDIM + kn + sg * 8, &Bh[bf][(wave*2+0)*1024]); \
            glds16(Wet + (bRow + 16) * KDIM + kn + sg * 8, &Bh[bf][(wave*2+1)*1024]); \
        } else {                                                                     \
            glds16(Wat + (bRow +  0) * CCH + sg * 8, &Bh[bf][(wave*2+0)*1024]);      \
            glds16(Wat + (bRow + 16) * CCH + sg * 8, &Bh[bf][(wave*2+1)*1024]);      \
        }                                                                            \
    }

    /* prologue: B(0), A(0), A(1) -> per-wave queue [B0,B0,A0,A0,A1,A1] */
    STG_B(0)
    STG_A(0)
    STG_A(1)

    for (int kk = 0; kk < 33; ++kk) {
        /* retire A(kk) (issued 2 steps ago) + B(kk) (1 step ago); A(kk+1) flies */
        if (kk < 32) asm volatile("s_waitcnt vmcnt(2)" ::: "memory");
        else         asm volatile("s_waitcnt vmcnt(0)" ::: "memory");
        __builtin_amdgcn_s_barrier();
        __builtin_amdgcn_sched_barrier(0);

        if (kk + 1 <= 32) STG_B(kk + 1)
        if (kk + 2 <= 32) STG_A(kk + 2)

        const int cur3 = kk - (kk / 3) * 3;
        const int cur2 = kk & 1;
        const _Float16* Ah = (const _Float16*)Ab[cur3];
        const _Float16* Bp = (const _Float16*)Bh[cur2];
        half8_t af[4], bf4[4];
#pragma unroll
        for (int i = 0; i < 4; ++i) {
            const int row = wm + i * 16 + c16;
            af[i] = *(const half8_t*)(Ah + (row >> 4) * 512 + (quad * 16 + c16) * 8);
        }
#pragma unroll
        for (int j = 0; j < 4; ++j) {
            const int row = wn + j * 16 + c16;
            bf4[j] = *(const half8_t*)(Bp + (row >> 4) * 512 + (quad * 16 + c16) * 8);
        }
#pragma unroll
        for (int i = 0; i < 4; ++i)
#pragma unroll
            for (int j = 0; j < 4; ++j)
                acc[i][j] = __builtin_amdgcn_mfma_f32_16x16x32_f16(af[i], bf4[j], acc[i][j], 0, 0, 0);
    }
#undef STG_A
#undef STG_B
    __syncthreads();   /* all waves done reading LDS before epilogue reuse */

    /* epilogue: + dterm, tanh, *g, 16-lane reduce, combine 2 n-waves */
    float* e_lds = (float*)&Bh[0][0];   /* [128][2] floats */
#pragma unroll
    for (int i = 0; i < 4; ++i) {
#pragma unroll
        for (int r = 0; r < 4; ++r) {
            const int rloc = wm + i * 16 + quad * 4 + r;
            const bool hi = (m0 + rloc) >= lim;
            float s = 0.f;
#pragma unroll
            for (int j = 0; j < 4; ++j)
                s += tanh_fast(acc[i][j][r] + (hi ? dt1[j] : dt0[j])) * g[j];
#pragma unroll
            for (int off = 1; off < 16; off <<= 1) s += __shfl_xor(s, off);
            if (c16 == 0) e_lds[rloc * 2 + (wave & 1)] = s;
        }
    }
    __syncthreads();
    if (tid < 128) {
        const float2 q = ((const float2*)e_lds)[tid];
        epart[nc * ROWS + m0 + tid] = q.x + q.y;
    }
}

/* fallback-path GEMM (fp32 A), original 2-buffer structure */
template<bool F16A>
__global__ __launch_bounds__(256, F16A ? 4 : 3)
void k_gemm_e(const void* __restrict__ encv,
              const _Float16* __restrict__ Wet,
              const void* __restrict__ convv,
              const _Float16* __restrict__ Wat,
              const float* __restrict__ dterm,
              const float* __restrict__ gvec,
              float* __restrict__ epart) {
    constexpr int ABYTES = F16A ? 8192 : 16384;
    __shared__ __attribute__((aligned(16))) char     Ab[2][ABYTES];
    __shared__ __attribute__((aligned(16))) _Float16 Bh[2][128 * 32];

    const int tid  = threadIdx.x;
    const int blk  = blockIdx.x;
    int nc, mt;
    if (blk < 1984) { nc = (blk >> 3) & 3; mt = (blk >> 5) * 8 + (blk & 7); }
    else            { int r = blk - 1984; nc = r >> 2; mt = 496 + (r & 3); }
    const int m0 = mt * 128, n0 = nc * 128;

    const int wave = tid >> 6, lane = tid & 63;
    const int quad = lane >> 4, c16 = lane & 15;
    const int wm = (wave >> 1) * 64, wn = (wave & 1) * 64;

    const int rlB = lane & 15, sgB = lane >> 4;
    const int rlA = F16A ? (lane & 15) : (lane & 7);
    const int sgA = F16A ? (lane >> 4) : (lane >> 3);
    constexpr int AISS = F16A ? 2 : 4;
    constexpr int ARPC = F16A ? 16 : 8;
    constexpr int AEPS = F16A ? 8 : 4;

    const _Float16* encH = (const _Float16*)encv;
    const float*    encF = (const float*)encv;
    const _Float16* cvH  = (const _Float16*)convv;
    const float*    cvF  = (const float*)convv;

    const size_t aRow = (size_t)(m0 + wave * 32 + rlA);
    const size_t bRow = (size_t)(n0 + wave * 32 + rlB);

    float g[4], dt0[4], dt1[4];
    const int b0 = m0 / T_LEN, b1 = (m0 + 127) / T_LEN;
    const int lim = (b0 + 1) * T_LEN;
#pragma unroll
    for (int j = 0; j < 4; ++j) {
        const int col = n0 + wn + j * 16 + c16;
        g[j]   = gvec[col];
        dt0[j] = dterm[b0 * ADIM + col];
        dt1[j] = dterm[b1 * ADIM + col];
    }

    float4_t acc[4][4];
#pragma unroll
    for (int i = 0; i < 4; ++i)
#pragma unroll
        for (int j = 0; j < 4; ++j) acc[i][j] = (float4_t){0.f, 0.f, 0.f, 0.f};

#define STAGE_A(buf, base, stride, k0)                                              \
    _Pragma("unroll")                                                               \
    for (int i = 0; i < AISS; ++i)                                                  \
        glds16((base) + ((aRow + i * ARPC) * (stride)) + (k0) + sgA * AEPS,         \
               &Ab[buf][(wave * AISS + i) * 1024]);
#define STAGE_B(buf, base, stride, k0)                                              \
    _Pragma("unroll")                                                               \
    for (int i = 0; i < 2; ++i)                                                     \
        glds16((base) + ((bRow + i * 16) * (stride)) + (k0) + sgB * 8,              \
               (char*)&Bh[buf][0] + (wave * 2 + i) * 1024);

    if (F16A) { STAGE_A(0, encH, KDIM, 0) } else { STAGE_A(0, encF, KDIM, 0) }
    STAGE_B(0, Wet, KDIM, 0)
    __syncthreads();

    for (int kk = 0; kk < 33; ++kk) {
        const int cur = kk & 1, nxt = cur ^ 1;
        if (kk < 31) {
            const int kn = (kk + 1) * 32;
            if (F16A) { STAGE_A(nxt, encH, KDIM, kn) } else { STAGE_A(nxt, encF, KDIM, kn) }
            STAGE_B(nxt, Wet, KDIM, kn)
        } else if (kk == 31) {
            if (F16A) { STAGE_A(nxt, cvH, CCH, 0) } else { STAGE_A(nxt, cvF, CCH, 0) }
            STAGE_B(nxt, Wat, CCH, 0)
        }
        half8_t af[4], bf[4];
        if (F16A) {
            const _Float16* Ah = (const _Float16*)Ab[cur];
#pragma unroll
            for (int i = 0; i < 4; ++i) {
                const int row = wm + i * 16 + c16;
                af[i] = *(const half8_t*)(Ah + (row >> 4) * 512 + (quad * 16 + c16) * 8);
            }
        } else {
            const float* Afp = (const float*)Ab[cur];
#pragma unroll
            for (int i = 0; i < 4; ++i) {
                const int row = wm + i * 16 + c16;
                const float* cb = Afp + (row >> 3) * 256 + (row & 7) * 4;
                float4_t u0 = *(const float4_t*)(cb + (2 * quad) * 32);
                float4_t u1 = *(const float4_t*)(cb + (2 * quad + 1) * 32);
                af[i] = pack8(u0, u1);
            }
        }
#pragma unroll
        for (int j = 0; j < 4; ++j) {
            const int row = wn + j * 16 + c16;
            bf[j] = *(const half8_t*)(&Bh[cur][0] + (row >> 4) * 512 + (quad * 16 + c16) * 8);
        }
#pragma unroll
        for (int i = 0; i < 4; ++i)
#pragma unroll
            for (int j = 0; j < 4; ++j)
                acc[i][j] = __builtin_amdgcn_mfma_f32_16x16x32_f16(af[i], bf[j], acc[i][j], 0, 0, 0);
        __syncthreads();
    }

    float* e_lds = (float*)&Bh[0][0];
#pragma unroll
    for (int i = 0; i < 4; ++i) {
#pragma unroll
        for (int r = 0; r < 4; ++r) {
            const int rloc = wm + i * 16 + quad * 4 + r;
            const bool hi = (m0 + rloc) >= lim;
            float s = 0.f;
#pragma unroll
            for (int j = 0; j < 4; ++j)
                s += tanh_fast(acc[i][j][r] + (hi ? dt1[j] : dt0[j])) * g[j];
#pragma unroll
            for (int off = 1; off < 16; off <<= 1) s += __shfl_xor(s, off);
            if (c16 == 0) e_lds[rloc * 2 + (wave & 1)] = s;
        }
    }
    __syncthreads();
    if (tid < 128) {
        const float2 q = ((const float2*)e_lds)[tid];
        epart[nc * ROWS + m0 + tid] = q.x + q.y;
    }
#undef STAGE_A
#undef STAGE_B
}

/* softmax over T; logit = 2*sum_nc epart, masked -> -2e15.
 * 1024 thr (16 waves): 2 strided rounds instead of 4 -> shorter dependent
 * load chains in the latency-bound 32-block launch. */
__global__ __launch_bounds__(1024) void k_softmax(const float* __restrict__ epart,
                                                  const int* __restrict__ enc_len,
                                                  float* __restrict__ attn) {
    __shared__ float ex[T_LEN];
    __shared__ float red[16];
    const int b = blockIdx.x, tid = threadIdx.x;
    const int len = enc_len[b];
    float lmax = -3.4e38f;
    for (int t = tid; t < T_LEN; t += 1024) {
        float e = epart[b * T_LEN + t] + epart[ROWS + b * T_LEN + t]
                + epart[2 * ROWS + b * T_LEN + t] + epart[3 * ROWS + b * T_LEN + t];
        float lg = (t < len) ? 2.f * e : -2e15f;
        ex[t] = lg;
        lmax = fmaxf(lmax, lg);
    }
    for (int off = 1; off < 64; off <<= 1) lmax = fmaxf(lmax, __shfl_xor(lmax, off));
    if ((tid & 63) == 0) red[tid >> 6] = lmax;
    __syncthreads();
    float m = red[0];
#pragma unroll
    for (int i = 1; i < 16; ++i) m = fmaxf(m, red[i]);
    float lsum = 0.f;
    for (int t = tid; t < T_LEN; t += 1024) {
        float p = __expf(ex[t] - m);
        ex[t] = p;
        lsum += p;
    }
    for (int off = 1; off < 64; off <<= 1) lsum += __shfl_xor(lsum, off);
    __syncthreads();
    if ((tid & 63) == 0) red[tid >> 6] = lsum;
    __syncthreads();
    float sm = 0.f;
#pragma unroll
    for (int i = 0; i < 16; ++i) sm += red[i];
    const float inv = 1.f / sm;
    for (int t = tid; t < T_LEN; t += 1024) attn[b * T_LEN + t] = ex[t] * inv;
}

/* c partial from f16 enc copy */
__global__ __launch_bounds__(256) void k_cpart_h(const float* __restrict__ attn,
                                                 const _Float16* __restrict__ encH,
                                                 float* __restrict__ cpart) {
    const int b = blockIdx.y, tc = blockIdx.x, tid = threadIdx.x;
    const int t0 = tc * 125;
    float4_t s = (float4_t){0.f, 0.f, 0.f, 0.f};
    const half4_t* ep = (const half4_t*)(encH + (size_t)b * T_LEN * KDIM) + tid;
    const float* ap = attn + b * T_LEN + t0;
#pragma unroll 5
    for (int tt = 0; tt < 125; ++tt) {
        const float w = ap[tt];
        half4_t v = ep[(size_t)(t0 + tt) * 256];
        s.x += w * (float)v[0]; s.y += w * (float)v[1];
        s.z += w * (float)v[2]; s.w += w * (float)v[3];
    }
    *(float4_t*)&cpart[(size_t)(tc * BATCH + b) * KDIM + tid * 4] = s;
}

/* c partial from fp32 enc (fallback) */
__global__ __launch_bounds__(256) void k_cpart_f(const float* __restrict__ attn,
                                                 const float* __restrict__ enc,
                                                 float* __restrict__ cpart) {
    const int b = blockIdx.y, tc = blockIdx.x, tid = threadIdx.x;
    const int t0 = tc * 125;
    float4_t s = (float4_t){0.f, 0.f, 0.f, 0.f};
    const float4_t* ep = (const float4_t*)(enc + (size_t)b * T_LEN * KDIM) + tid;
    const float* ap = attn + b * T_LEN + t0;
#pragma unroll 5
    for (int tt = 0; tt < 125; ++tt) {
        const float w = ap[tt];
        float4_t v = ep[(size_t)(t0 + tt) * 256];
        s += v * w;
    }
    *(float4_t*)&cpart[(size_t)(tc * BATCH + b) * KDIM + tid * 4] = s;
}

/* out_c[b][o] = b_o[o] + sum_d cm[d] * W_o[d][o]; grid (32,16) x 256.
 * Block (b, og): 64 o-columns; threads = 64 o x 4 d-slices (256 d each),
 * LDS reduce across slices. 512 blocks (2/CU) and 256 loads/thread vs the
 * old 128 blocks x 1024 serial loads -> 4x latency-hiding. */
__global__ __launch_bounds__(256) void k_out_w(const float* __restrict__ cpart,
                                               const float* __restrict__ W_o,
                                               const float* __restrict__ b_o,
                                               float* __restrict__ out_c) {
    __shared__ float cm[KDIM];
    __shared__ float part[256];
    const int b = blockIdx.x, og = blockIdx.y, tid = threadIdx.x;
    for (int d = tid; d < KDIM; d += 256) {
        float s = 0.f;
#pragma unroll
        for (int p = 0; p < 16; ++p) s += cpart[(size_t)(p * BATCH + b) * KDIM + d];
        cm[d] = s;
    }
    __syncthreads();
    const int o  = og * 64 + (tid & 63);
    const int ds = tid >> 6;                       /* 0..3 -> d-range 256 */
    const float* wp = W_o + (size_t)(ds * 256) * KDIM + o;
    const float* cp = cm + ds * 256;
    float s = 0.f;
#pragma unroll 8
    for (int k = 0; k < 256; ++k) s += cp[k] * wp[(size_t)k * KDIM];
    part[tid] = s;
    __syncthreads();
    if (tid < 64)
        out_c[b * KDIM + o] = part[tid] + part[tid + 64] + part[tid + 128]
                            + part[tid + 192] + b_o[o];
}

extern "C" void kernel_launch(void* const* d_in, const int* in_sizes, int n_in,
                              void* d_out, int out_size, void* d_ws, size_t ws_size,
                              hipStream_t stream) {
    const float* enc      = (const float*)d_in[0];
    const int*   enc_len  = (const int*)d_in[1];
    const float* dec_h    = (const float*)d_in[2];
    const float* att_prev = (const float*)d_in[3];
    const float* W_enc    = (const float*)d_in[4];
    const float* b_enc    = (const float*)d_in[5];
    const float* W_dec    = (const float*)d_in[6];
    const float* b_dec    = (const float*)d_in[7];
    const float* W_att    = (const float*)d_in[8];
    const float* b_att    = (const float*)d_in[9];
    const float* conv_w   = (const float*)d_in[10];
    const float* gvec     = (const float*)d_in[11];
    const float* W_o      = (const float*)d_in[12];
    const float* b_o      = (const float*)d_in[13];

    float* out_c    = (float*)d_out;           /* 32*1024 */
    float* out_attn = out_c + BATCH * KDIM;    /* 32*2000 */

    char* ws = (char*)d_ws;
    _Float16* Wet = (_Float16*)(ws + OFF_WENCT);
    _Float16* Wat = (_Float16*)(ws + OFF_WATTT);

    const size_t needMain = (size_t)M_ENCH + (size_t)ROWS * KDIM * 2;
    const bool f16p = ws_size >= needMain;

    if (f16p) {
        _Float16* convH = (_Float16*)(ws + OFF_CONV);
        float*    dterm = (float*)(ws + M_DTERM);
        float*    epart = (float*)(ws + M_EPART);
        float*    cpart = (float*)(ws + M_CPART);
        _Float16* encH  = (_Float16*)(ws + M_ENCH);

        k_prep<<<1153 + 32000, 256, 0, stream>>>(W_enc, W_att, dec_h, W_dec, b_enc, b_dec,
                                                 b_att, att_prev, conv_w, enc,
                                                 Wet, Wat, dterm, convH, encH, 1);
        k_gemm_p<<<2000, 256, 0, stream>>>(encH, Wet, convH, Wat, dterm, gvec, epart);
        k_softmax<<<BATCH, 1024, 0, stream>>>(epart, enc_len, out_attn);
        k_cpart_h<<<dim3(16, BATCH), 256, 0, stream>>>(out_attn, encH, cpart);
        k_out_w<<<dim3(BATCH, 16), 256, 0, stream>>>(cpart, W_o, b_o, out_c);
    } else {
        float* convF = (float*)(ws + OFF_CONV);
        float* dterm = (float*)(ws + F_DTERM);
        float* epart = (float*)(ws + F_EPART);
        float* cpart = (float*)(ws + F_CPART);

        k_prep<<<1153, 256, 0, stream>>>(W_enc, W_att, dec_h, W_dec, b_enc, b_dec,
                                         b_att, att_prev, conv_w, enc,
                                         Wet, Wat, dterm, convF, (_Float16*)nullptr, 0);
        k_gemm_e<false><<<2000, 256, 0, stream>>>(enc, Wet, convF, Wat, dterm, gvec, epart);
        k_softmax<<<BATCH, 1024, 0, stream>>>(epart, enc_len, out_attn);
        k_cpart_f<<<dim3(16, BATCH), 256, 0, stream>>>(out_attn, enc, cpart);
        k_out_w<<<dim3(BATCH, 16), 256, 0, stream>>>(cpart, W_o, b_o, out_c);
    }
}